// Round 11
// baseline (362.536 us; speedup 1.0000x reference)
//
#include <hip/hip_runtime.h>
#include <math.h>

#define N_NODES 50000
#define N_EDGES 800000
#define G_GRAPHS 64
#define HDIM 128
#define HID 32
#define NCLS 10
#define BN_EPS 1e-5f
#define SLOPE 0.2f
#define NB_SCAN 196
#define STATS_STRIDE (256 + G_GRAPHS * HDIM)
#define DEFER_THR 8.0f

// bucket sort geometry
#define NBUCK 64
#define NPB 782              // nodes per bucket; 64*782 = 50048 >= N_NODES
#define CH 4096              // edges per scatter chunk
#define NCHUNK 196           // ceil(N_EDGES / CH)
#define NGB_GEMM 782         // gemm blocks: ceil(N_NODES/64)
#define CAP_OUT 13824        // per-bucket sort capacity (mean 12512, sigma 111)
#define NZ_DWORDS (64 + 3 * STATS_STRIDE + 64)   // bcnt | statsAll | bcur (contiguous)

typedef __attribute__((ext_vector_type(8))) short bf16x8;
typedef __attribute__((ext_vector_type(4))) float f32x4;

__device__ __forceinline__ float lrelu(float x) { return fmaxf(x, SLOPE * x); }

__device__ __forceinline__ unsigned short f2bf(float x) {
    unsigned int u = __float_as_uint(x);
    u = (u + 0x7fffu + ((u >> 16) & 1u)) >> 16;
    return (unsigned short)u;
}
__device__ __forceinline__ unsigned int pk2bf(float lo, float hi) {
    unsigned int r;
    asm("v_cvt_pk_bf16_f32 %0, %1, %2" : "=v"(r) : "v"(lo), "v"(hi));
    return r;
}
__device__ __forceinline__ float2 up2(unsigned int u) {
    return make_float2(__uint_as_float(u << 16), __uint_as_float(u & 0xffff0000u));
}
__device__ __forceinline__ float bf2f(unsigned short u) {
    return __uint_as_float((unsigned int)u << 16);
}
__device__ __forceinline__ int wl_index(int k, int c) {
    int lane = ((k >> 3) & 3) * 16 + (c & 15);
    return (((k >> 5) * 8 + (c >> 4)) * 64 + lane) * 8 + (k & 7);
}

// ---------------- MFMA GEMM body: Hb = bf16( X @ W' + fb' ) ----------------
template <bool XF32>
__device__ __forceinline__ void gemm_body(int bid, const void* __restrict__ Xv,
                                          const unsigned short* __restrict__ WL,
                                          const float* __restrict__ fb,
                                          unsigned short* __restrict__ Hb) {
    int t = threadIdx.x;
    int w = t >> 6, lane = t & 63;
    int i16 = lane & 15, kg = lane >> 4;
    int r0w = bid * 64 + w * 16;
    int row = r0w + i16;
    int rowc = row < N_NODES ? row : N_NODES - 1;

    f32x4 acc[8];
    #pragma unroll
    for (int cs = 0; cs < 8; ++cs) acc[cs] = (f32x4){0.f, 0.f, 0.f, 0.f};

    #pragma unroll
    for (int ks = 0; ks < 4; ++ks) {
        union { uint4 u; bf16x8 s; } af;
        if (XF32) {
            const float* xp = (const float*)Xv + (size_t)rowc * HDIM + ks * 32 + kg * 8;
            float4 v0 = *(const float4*)xp;
            float4 v1 = *(const float4*)(xp + 4);
            af.u.x = pk2bf(v0.x, v0.y);
            af.u.y = pk2bf(v0.z, v0.w);
            af.u.z = pk2bf(v1.x, v1.y);
            af.u.w = pk2bf(v1.z, v1.w);
        } else {
            const unsigned short* xp = (const unsigned short*)Xv + (size_t)rowc * HDIM + ks * 32 + kg * 8;
            af.u = *(const uint4*)xp;
        }
        #pragma unroll
        for (int cs = 0; cs < 8; ++cs) {
            union { uint4 u; bf16x8 s; } bw;
            bw.u = *(const uint4*)&WL[(((ks << 3) + cs) * 64 + lane) * 8];
            acc[cs] = __builtin_amdgcn_mfma_f32_16x16x32_bf16(af.s, bw.s, acc[cs], 0, 0, 0);
        }
    }
    #pragma unroll
    for (int cs = 0; cs < 8; ++cs) {
        int col = cs * 16 + i16;
        float bias = fb[col];
        #pragma unroll
        for (int p = 0; p < 4; ++p) {
            int r = r0w + kg * 4 + p;
            if (r < N_NODES) Hb[(size_t)r * HDIM + col] = f2bf(acc[cs][p] + bias);
        }
    }
}

template <bool XF32>
__global__ __launch_bounds__(256) void k_gemm_mfma(const void* __restrict__ Xv,
                                                   const unsigned short* __restrict__ WL,
                                                   const float* __restrict__ fb,
                                                   unsigned short* __restrict__ Hb) {
    gemm_body<XF32>(blockIdx.x, Xv, WL, fb, Hb);
}

// ---------------- prep: blocks 0..15 = layer-0 W prep; 16..19 = zero-fill; 20 = graph bounds ----------------
__global__ __launch_bounds__(256) void k_prep(const float* __restrict__ W,
                                              unsigned short* __restrict__ WL,
                                              unsigned int* __restrict__ zbase,
                                              const int* __restrict__ seg,
                                              int* __restrict__ gs) {
    int bid = blockIdx.x, t = threadIdx.x;
    if (bid < 16) {
        for (int idx = bid * 256 + t; idx < HDIM * HDIM; idx += 16 * 256) {
            int k = idx >> 7, c = idx & 127;
            WL[wl_index(k, c)] = f2bf(W[idx]);
        }
    } else if (bid < 20) {
        for (int i = (bid - 16) * 256 + t; i < NZ_DWORDS; i += 4 * 256) zbase[i] = 0u;
    } else {
        if (t <= G_GRAPHS) {
            int g = t;
            int lo = 0, hi = N_NODES;
            while (lo < hi) {
                int mid = (lo + hi) >> 1;
                if (seg[mid] < g) lo = mid + 1; else hi = mid;
            }
            gs[g] = lo;
        }
    }
}

// ---------------- mega0: bucket histogram (196) + gemm L0 (782) ----------------
__global__ __launch_bounds__(256) void k_mega0(const int* __restrict__ dst,
                                               int* __restrict__ bcnt,
                                               const unsigned short* __restrict__ WL0,
                                               const float* __restrict__ feat,
                                               const float* __restrict__ fb0,
                                               unsigned short* __restrict__ Hb) {
    __shared__ unsigned int h[NBUCK];
    int bid = blockIdx.x;
    int t = threadIdx.x;
    if (bid < NCHUNK) {
        if (t < NBUCK) h[t] = 0;
        __syncthreads();
        int base = bid * CH;
        #pragma unroll
        for (int e = 0; e < 16; ++e) {
            int i = base + e * 256 + t;
            if (i < N_EDGES) {
                int d = dst[i];
                atomicAdd(&h[d / NPB], 1u);
            }
        }
        __syncthreads();
        if (t < NBUCK && h[t]) atomicAdd(&bcnt[t], (int)h[t]);
    } else {
        gemm_body<true>(bid - NCHUNK, feat, WL0, fb0, Hb);
    }
}

// ---------------- scatter into buckets (local bbase scan; bcur is zero-based cursor) ----------------
__global__ __launch_bounds__(256) void k_bscatter(const int* __restrict__ dst,
                                                  const int* __restrict__ src,
                                                  const int* __restrict__ bcnt,
                                                  int* __restrict__ bcur,
                                                  unsigned int* __restrict__ gbuf) {
    __shared__ unsigned int hist[NBUCK];
    __shared__ unsigned int scanB[NBUCK + 1];
    __shared__ int gdelta[NBUCK];
    __shared__ unsigned int cur[NBUCK];
    __shared__ unsigned int ent[CH];
    __shared__ int bb[NBUCK];
    int t = threadIdx.x;
    int base = blockIdx.x * CH;
    unsigned int eb[16], een[16];
    if (t < NBUCK) {
        int v = bcnt[t];
        int inc = v;
        #pragma unroll
        for (int off = 1; off < 64; off <<= 1) {
            int u = __shfl_up(inc, off);
            if (t >= off) inc += u;
        }
        bb[t] = inc - v;   // exclusive global bucket base
        hist[t] = 0;
    }
    __syncthreads();
    #pragma unroll
    for (int e = 0; e < 16; ++e) {
        int i = base + e * 256 + t;
        if (i < N_EDGES) {
            int d = dst[i];
            int s = src[i];
            int b = d / NPB;
            eb[e] = (unsigned int)b;
            een[e] = ((unsigned int)(d - b * NPB) << 17) | (unsigned int)s;
            atomicAdd(&hist[b], 1u);
        } else {
            eb[e] = 0xFFFFFFFFu;
            een[e] = 0;
        }
    }
    __syncthreads();
    if (t < NBUCK) {
        unsigned int v = hist[t];
        unsigned int inc = v;
        #pragma unroll
        for (int off = 1; off < 64; off <<= 1) {
            unsigned int u = __shfl_up(inc, off);
            if ((t & 63) >= off) inc += u;
        }
        scanB[t + 1] = inc;
        if (t == 0) scanB[0] = 0;
    }
    __syncthreads();
    if (t < NBUCK) {
        unsigned int hv = hist[t];
        int gb = bb[t] + (hv ? atomicAdd(&bcur[t], (int)hv) : 0);
        gdelta[t] = gb - (int)scanB[t];
        cur[t] = 0;
    }
    __syncthreads();
    #pragma unroll
    for (int e = 0; e < 16; ++e) {
        if (eb[e] < NBUCK) {
            unsigned int pos = scanB[eb[e]] + atomicAdd(&cur[eb[e]], 1u);
            ent[pos] = een[e];
        }
    }
    __syncthreads();
    unsigned int cntE = scanB[NBUCK];
    #pragma unroll
    for (int e = 0; e < 16; ++e) {
        unsigned int i = (unsigned int)(e * 256 + t);
        if (i < cntE) {
            int lo2 = 0, hi2 = NBUCK;
            while (hi2 - lo2 > 1) {
                int mid = (lo2 + hi2) >> 1;
                if (scanB[mid] <= i) lo2 = mid; else hi2 = mid;
            }
            gbuf[gdelta[lo2] + i] = ent[i];
        }
    }
}

// ---------------- per-bucket counting sort -> ssrc + rowptr (local bbase scan) ----------------
__global__ __launch_bounds__(256) void k_bsort(const int* __restrict__ bcnt,
                                               const unsigned int* __restrict__ gbuf,
                                               int* __restrict__ ssrc,
                                               int* __restrict__ rowptr) {
    extern __shared__ unsigned int sout[];   // CAP_OUT
    __shared__ unsigned int hist[NPB];
    __shared__ unsigned int sbase[NPB + 1];
    __shared__ unsigned int cur[NPB];
    __shared__ unsigned int wsum[4];
    __shared__ int sbb[NBUCK + 1];
    int b = blockIdx.x;
    int t = threadIdx.x;
    if (t < NBUCK) {
        int v = bcnt[t];
        int inc = v;
        #pragma unroll
        for (int off = 1; off < 64; off <<= 1) {
            int u = __shfl_up(inc, off);
            if (t >= off) inc += u;
        }
        sbb[t + 1] = inc;
        if (t == 0) sbb[0] = 0;
    }
    __syncthreads();
    int lo = sbb[b], hi = sbb[b + 1];
    int cnt = hi - lo;
    if (cnt > CAP_OUT) cnt = CAP_OUT;
    for (int i = t; i < NPB; i += 256) { hist[i] = 0; cur[i] = 0; }
    __syncthreads();
    for (int i = t; i < cnt; i += 256) {
        unsigned int e = gbuf[lo + i];
        atomicAdd(&hist[e >> 17], 1u);
    }
    __syncthreads();
    unsigned int loc[4], s = 0;
    #pragma unroll
    for (int j = 0; j < 4; ++j) {
        int idx = t * 4 + j;
        loc[j] = idx < NPB ? hist[idx] : 0;
        s += loc[j];
    }
    unsigned int inc = s;
    #pragma unroll
    for (int off = 1; off < 64; off <<= 1) {
        unsigned int u = __shfl_up(inc, off);
        if ((t & 63) >= off) inc += u;
    }
    int wid = t >> 6;
    if ((t & 63) == 63) wsum[wid] = inc;
    __syncthreads();
    if (t == 0) {
        unsigned int r = 0;
        #pragma unroll
        for (int w = 0; w < 4; ++w) { unsigned int x = wsum[w]; wsum[w] = r; r += x; }
    }
    __syncthreads();
    unsigned int excl = inc - s + wsum[wid];
    #pragma unroll
    for (int j = 0; j < 4; ++j) {
        int idx = t * 4 + j;
        if (idx < NPB) { sbase[idx] = excl; excl += loc[j]; }
    }
    if (t == 255) sbase[NPB] = excl;
    __syncthreads();
    for (int v = t; v < NPB; v += 256) {
        int nid = b * NPB + v;
        if (nid < N_NODES) rowptr[nid] = lo + (int)sbase[v];
    }
    if (b == NBUCK - 1 && t == 0) rowptr[N_NODES] = N_EDGES;
    for (int i = t; i < cnt; i += 256) {
        unsigned int e = gbuf[lo + i];
        unsigned int dl = e >> 17;
        unsigned int pos = sbase[dl] + atomicAdd(&cur[dl], 1u);
        if (pos < (unsigned int)CAP_OUT) sout[pos] = e & 0x1FFFFu;
    }
    __syncthreads();
    for (int i = t; i < cnt; i += 256) ssrc[lo + i] = (int)sout[i];
}

// ---------------- fused edge kernel: 4 edge-slots/wave, lrelu-split score ----------------
// lrelu(x)*a = 0.6*a*x + 0.4*a*|x|  ->  score = dot(at06,el) + dot(at04,|el+er|) + cER
__global__ __launch_bounds__(256) void k_edge(const unsigned short* __restrict__ Hb,
                                              const int* __restrict__ row_ptr,
                                              const int* __restrict__ ssrc,
                                              const float* __restrict__ attn,
                                              const float* __restrict__ ob,
                                              unsigned short* __restrict__ Yb) {
    int wid = blockIdx.x * 4 + (threadIdx.x >> 6);
    if (wid >= N_NODES) return;
    int lane = threadIdx.x & 63;
    int slot = lane >> 4, s16 = lane & 15;
    int d0 = s16 << 3;
    int beg = row_ptr[wid], end = row_ptr[wid + 1];
    int deg = end - beg;
    if (deg == 0) {
        if (slot == 0) {
            float4 o0 = *(const float4*)&ob[d0];
            float4 o1 = *(const float4*)&ob[d0 + 4];
            uint4 w;
            w.x = pk2bf(fmaxf(o0.x, 0.f), fmaxf(o0.y, 0.f));
            w.y = pk2bf(fmaxf(o0.z, 0.f), fmaxf(o0.w, 0.f));
            w.z = pk2bf(fmaxf(o1.x, 0.f), fmaxf(o1.y, 0.f));
            w.w = pk2bf(fmaxf(o1.z, 0.f), fmaxf(o1.w, 0.f));
            *(uint4*)&Yb[(size_t)wid * HDIM + d0] = w;
        }
        return;
    }
    float er[8], at06[8], at04[8];
    {
        uint4 e = *(const uint4*)&Hb[(size_t)wid * HDIM + d0];
        unsigned int uu[4] = {e.x, e.y, e.z, e.w};
        #pragma unroll
        for (int i = 0; i < 4; ++i) {
            float2 f = up2(uu[i]);
            er[2 * i] = f.x; er[2 * i + 1] = f.y;
        }
        float4 a0 = *(const float4*)&attn[d0];
        float4 a1 = *(const float4*)&attn[d0 + 4];
        float av[8] = {a0.x, a0.y, a0.z, a0.w, a1.x, a1.y, a1.z, a1.w};
        #pragma unroll
        for (int d = 0; d < 8; ++d) {
            at06[d] = 0.6f * av[d];
            at04[d] = 0.4f * av[d];
        }
    }
    // per-node/head constant: cER = dot(at06, er), reduced over the 4-lane head group
    float cER = 0.f;
    #pragma unroll
    for (int d = 0; d < 8; ++d) cER = fmaf(at06[d], er[d], cER);
    cER += __shfl_xor(cER, 1);
    cER += __shfl_xor(cER, 2);

    const float NINF = __int_as_float(0xff800000);
    float m = -1e30f, den = 0.f;
    float acc[8] = {0.f, 0.f, 0.f, 0.f, 0.f, 0.f, 0.f, 0.f};
    int nit = (deg + 3) >> 2;
    int j = beg + slot;
    int sa;
    uint4 elc;
    {
        int jc0 = j < end ? j : beg;
        int jc1 = (j + 4) < end ? (j + 4) : beg;
        int s0 = ssrc[jc0];
        sa = ssrc[jc1];
        elc = *(const uint4*)&Hb[(size_t)s0 * HDIM + d0];
    }
    for (int it = 0; it < nit; ++it) {
        int jc2 = (j + 8) < end ? (j + 8) : beg;
        int sb = ssrc[jc2];
        uint4 eln = *(const uint4*)&Hb[(size_t)sa * HDIM + d0];
        bool act = j < end;
        float el[8];
        {
            unsigned int uu[4] = {elc.x, elc.y, elc.z, elc.w};
            #pragma unroll
            for (int i = 0; i < 4; ++i) {
                float2 f = up2(uu[i]);
                el[2 * i] = f.x; el[2 * i + 1] = f.y;
            }
        }
        float p = 0.f, pa = 0.f;
        #pragma unroll
        for (int d = 0; d < 8; ++d) {
            p = fmaf(at06[d], el[d], p);
            pa = fmaf(at04[d], fabsf(el[d] + er[d]), pa);  // fabs folds to src modifier
        }
        p += pa;
        p += __shfl_xor(p, 1);
        p += __shfl_xor(p, 2);          // 4-lane head-dot reduce
        float e = act ? (p + cER) : NINF;
        if (__all(e - m <= DEFER_THR)) {   // defer-max: no rescale
            float q = __expf(e - m);
            den += q;
            #pragma unroll
            for (int d = 0; d < 8; ++d) acc[d] = fmaf(el[d], q, acc[d]);
        } else {
            float nm = fmaxf(m, e);
            float r = __expf(m - nm);
            float q = __expf(e - nm);
            den = fmaf(den, r, q);
            #pragma unroll
            for (int d = 0; d < 8; ++d) acc[d] = fmaf(acc[d], r, el[d] * q);
            m = nm;
        }
        elc = eln; sa = sb; j += 4;
    }
    // associative online-softmax merge across the 4 slots
    #pragma unroll
    for (int st = 16; st <= 32; st <<= 1) {
        float m2 = __shfl_xor(m, st);
        float den2 = __shfl_xor(den, st);
        float nm = fmaxf(m, m2);
        float r1 = __expf(m - nm);
        float r2 = __expf(m2 - nm);
        den = den * r1 + den2 * r2;
        #pragma unroll
        for (int d = 0; d < 8; ++d) {
            float a2 = __shfl_xor(acc[d], st);
            acc[d] = acc[d] * r1 + a2 * r2;
        }
        m = nm;
    }
    if (slot == 0) {
        float inv = den > 0.f ? 1.f / den : 0.f;
        float4 o0 = *(const float4*)&ob[d0];
        float4 o1 = *(const float4*)&ob[d0 + 4];
        float o[8] = {o0.x, o0.y, o0.z, o0.w, o1.x, o1.y, o1.z, o1.w};
        float r[8];
        #pragma unroll
        for (int d = 0; d < 8; ++d) r[d] = fmaxf(fmaf(acc[d], inv, o[d]), 0.f);
        uint4 w;
        w.x = pk2bf(r[0], r[1]);
        w.y = pk2bf(r[2], r[3]);
        w.z = pk2bf(r[4], r[5]);
        w.w = pk2bf(r[6], r[7]);
        *(uint4*)&Yb[(size_t)wid * HDIM + d0] = w;
    }
}

// ---------------- fused BN stats + per-graph sum pool ----------------
__global__ __launch_bounds__(256) void k_stats_pool(const unsigned short* __restrict__ Yb,
                                                    const int* __restrict__ seg,
                                                    float* __restrict__ sums,
                                                    float* __restrict__ sumsq,
                                                    float* __restrict__ pooled) {
    __shared__ float4 red[256];
    __shared__ int sseg[256];
    int t = threadIdx.x;
    int r0 = blockIdx.x * 256;
    if (r0 + t < N_NODES) sseg[t] = seg[r0 + t];
    __syncthreads();
    int c4 = t & 31, rh = t >> 5;
    int rend = r0 + 256 < N_NODES ? r0 + 256 : N_NODES;
    float sx = 0.f, sy = 0.f, sz = 0.f, sw = 0.f;
    float qx = 0.f, qy = 0.f, qz = 0.f, qw = 0.f;
    int curg = -1;
    float rx = 0.f, ry = 0.f, rz = 0.f, rw = 0.f;
    for (int r = r0 + rh; r < rend; r += 8) {
        ushort4 v = *(const ushort4*)&Yb[(size_t)r * HDIM + c4 * 4];
        float x0 = bf2f(v.x), x1 = bf2f(v.y), x2 = bf2f(v.z), x3 = bf2f(v.w);
        sx += x0; sy += x1; sz += x2; sw += x3;
        qx = fmaf(x0, x0, qx); qy = fmaf(x1, x1, qy);
        qz = fmaf(x2, x2, qz); qw = fmaf(x3, x3, qw);
        int g = sseg[r - r0];
        if (g != curg) {
            if (curg >= 0) {
                float* pp = &pooled[curg * HDIM + c4 * 4];
                atomicAdd(pp + 0, rx); atomicAdd(pp + 1, ry);
                atomicAdd(pp + 2, rz); atomicAdd(pp + 3, rw);
            }
            curg = g;
            rx = x0; ry = x1; rz = x2; rw = x3;
        } else {
            rx += x0; ry += x1; rz += x2; rw += x3;
        }
    }
    if (curg >= 0) {
        float* pp = &pooled[curg * HDIM + c4 * 4];
        atomicAdd(pp + 0, rx); atomicAdd(pp + 1, ry);
        atomicAdd(pp + 2, rz); atomicAdd(pp + 3, rw);
    }
    red[t] = make_float4(sx, sy, sz, sw);
    __syncthreads();
    if (rh == 0) {
        float4 tot = red[c4];
        #pragma unroll
        for (int i = 1; i < 8; ++i) {
            float4 o = red[i * 32 + c4];
            tot.x += o.x; tot.y += o.y; tot.z += o.z; tot.w += o.w;
        }
        float* sp = &sums[c4 * 4];
        atomicAdd(sp + 0, tot.x); atomicAdd(sp + 1, tot.y);
        atomicAdd(sp + 2, tot.z); atomicAdd(sp + 3, tot.w);
    }
    __syncthreads();
    red[t] = make_float4(qx, qy, qz, qw);
    __syncthreads();
    if (rh == 0) {
        float4 tot = red[c4];
        #pragma unroll
        for (int i = 1; i < 8; ++i) {
            float4 o = red[i * 32 + c4];
            tot.x += o.x; tot.y += o.y; tot.z += o.z; tot.w += o.w;
        }
        float* sp = &sumsq[c4 * 4];
        atomicAdd(sp + 0, tot.x); atomicAdd(sp + 1, tot.y);
        atomicAdd(sp + 2, tot.z); atomicAdd(sp + 3, tot.w);
    }
}

// ---------------- W-fold only (critical path): blocks 0..63 fold W, block 64 folds fb ----------------
__global__ __launch_bounds__(256) void k_fold(const float* __restrict__ sums,
                                              const float* __restrict__ sumsq,
                                              const float* __restrict__ bng,
                                              const float* __restrict__ bnb,
                                              const float* __restrict__ Wnext,
                                              const float* __restrict__ fbnext,
                                              unsigned short* __restrict__ WLnext,
                                              float* __restrict__ Fbnext) {
    __shared__ float sA[HDIM], sB[HDIM];
    int t = threadIdx.x;
    if (t < HDIM) {
        float mu = sums[t] * (1.f / N_NODES);
        float var = fmaxf(sumsq[t] * (1.f / N_NODES) - mu * mu, 0.f);
        float inv = rsqrtf(var + BN_EPS);
        float a = bng[t] * inv;
        sA[t] = a;
        sB[t] = bnb[t] - a * mu;
    }
    __syncthreads();
    if (blockIdx.x < 64) {
        int idx = blockIdx.x * 256 + t;
        int k = idx >> 7, c = idx & 127;
        WLnext[wl_index(k, c)] = f2bf(sA[k] * Wnext[idx]);
    } else if (t < HDIM) {
        float a = fbnext[t];
        for (int k = 0; k < HDIM; ++k) a = fmaf(sB[k], Wnext[k * HDIM + t], a);
        Fbnext[t] = a;
    }
}

// ---------------- deferred pooled heads: one block per graph, all 3 layers ----------------
__global__ __launch_bounds__(256) void k_heads1(const float* __restrict__ statsAll,
                                                const int* __restrict__ gs,
                                                const float* __restrict__ bng0, const float* __restrict__ bnb0,
                                                const float* __restrict__ bng1, const float* __restrict__ bnb1,
                                                const float* __restrict__ bng2, const float* __restrict__ bnb2,
                                                const float* __restrict__ lw0, const float* __restrict__ lb0,
                                                const float* __restrict__ lw1, const float* __restrict__ lb1,
                                                const float* __restrict__ lw2, const float* __restrict__ lb2,
                                                float* __restrict__ pl_all) {
    __shared__ float sA3[3][HDIM], sB3[3][HDIM];
    __shared__ float red[8][HID];
    int g = blockIdx.x, t = threadIdx.x;
    const float* bngs[3] = {bng0, bng1, bng2};
    const float* bnbs[3] = {bnb0, bnb1, bnb2};
    const float* lws[3] = {lw0, lw1, lw2};
    const float* lbs[3] = {lb0, lb1, lb2};
    if (t < HDIM) {
        #pragma unroll
        for (int l = 0; l < 3; ++l) {
            const float* su = statsAll + (size_t)l * STATS_STRIDE;
            float mu = su[t] * (1.f / N_NODES);
            float var = fmaxf(su[128 + t] * (1.f / N_NODES) - mu * mu, 0.f);
            float inv = rsqrtf(var + BN_EPS);
            float a = bngs[l][t] * inv;
            sA3[l][t] = a;
            sB3[l][t] = bnbs[l][t] - a * mu;
        }
    }
    __syncthreads();
    float cnt = (float)(gs[g + 1] - gs[g]);
    int col = t & 31, kq = t >> 5;
    #pragma unroll
    for (int l = 0; l < 3; ++l) {
        const float* pg = statsAll + (size_t)l * STATS_STRIDE + 256 + (size_t)g * HDIM;
        float part = 0.f;
        #pragma unroll
        for (int kk = 0; kk < 16; ++kk) {
            int k = kq * 16 + kk;
            float pin = fmaf(sA3[l][k], pg[k], cnt * sB3[l][k]);
            part = fmaf(pin, lws[l][k * HID + col], part);
        }
        red[kq][col] = part;
        __syncthreads();
        if (kq == 0) {
            float s = red[0][col] + red[1][col] + red[2][col] + red[3][col]
                    + red[4][col] + red[5][col] + red[6][col] + red[7][col];
            pl_all[((size_t)l * G_GRAPHS + g) * HID + col] = fmaxf(s + lbs[l][col], 0.f);
        }
        __syncthreads();
    }
}

// ---------------- final: BN(pl) -> MLP -> BN -> relu -> logits -> log_softmax ----------------
__global__ __launch_bounds__(256) void k_final(const float* __restrict__ pl_all,
                                               const float* __restrict__ lg0, const float* __restrict__ lbt0,
                                               const float* __restrict__ lg1, const float* __restrict__ lbt1,
                                               const float* __restrict__ lg2, const float* __restrict__ lbt2,
                                               const float* __restrict__ mw1,
                                               const float* __restrict__ mg,
                                               const float* __restrict__ mb,
                                               const float* __restrict__ mw2,
                                               float* __restrict__ out) {
    __shared__ float pl3[3 * G_GRAPHS * HID];   // 24 KB
    __shared__ float w1[3 * HID * HID];         // 12 KB
    __shared__ float hm[G_GRAPHS][HID];         // 8 KB
    __shared__ float sc[96], sh[96];
    __shared__ float lgt[G_GRAPHS][NCLS];
    __shared__ float w2[HID * NCLS];
    int t = threadIdx.x;
    const float* lgs[3] = {lg0, lg1, lg2};
    const float* lbts[3] = {lbt0, lbt1, lbt2};
    for (int i = t; i < 3 * G_GRAPHS * HID; i += 256) pl3[i] = pl_all[i];
    for (int i = t; i < 3 * HID * HID; i += 256) w1[i] = mw1[i];
    for (int i = t; i < HID * NCLS; i += 256) w2[i] = mw2[i];
    __syncthreads();
    if (t < 96) {
        int l = t >> 5, c = t & 31;
        float s = 0.f, q = 0.f;
        for (int g = 0; g < G_GRAPHS; ++g) {
            float v = pl3[(l * G_GRAPHS + g) * HID + c];
            s += v; q = fmaf(v, v, q);
        }
        float mu = s * (1.f / G_GRAPHS);
        float var = fmaxf(q * (1.f / G_GRAPHS) - mu * mu, 0.f);
        float inv = rsqrtf(var + BN_EPS);
        float a = lgs[l][c] * inv;
        sc[t] = a;
        sh[t] = lbts[l][c] - a * mu;
    }
    __syncthreads();
    for (int i = t; i < 3 * G_GRAPHS * HID; i += 256) {
        int l = i / (G_GRAPHS * HID);
        int c = i & 31;
        pl3[i] = fmaf(pl3[i], sc[l * 32 + c], sh[l * 32 + c]);
    }
    __syncthreads();
    for (int i = t; i < G_GRAPHS * HID; i += 256) {
        int g = i >> 5, c = i & 31;
        float acc = 0.f;
        #pragma unroll
        for (int l = 0; l < 3; ++l)
            for (int k = 0; k < HID; ++k)
                acc = fmaf(pl3[(l * G_GRAPHS + g) * HID + k], w1[(l * HID + k) * HID + c], acc);
        hm[g][c] = acc;
    }
    __syncthreads();
    if (t < HID) {
        float s = 0.f, q = 0.f;
        for (int g = 0; g < G_GRAPHS; ++g) {
            float v = hm[g][t];
            s += v; q = fmaf(v, v, q);
        }
        float mu = s * (1.f / G_GRAPHS);
        float var = fmaxf(q * (1.f / G_GRAPHS) - mu * mu, 0.f);
        float inv = rsqrtf(var + BN_EPS);
        float a = mg[t] * inv;
        sc[t] = a;
        sh[t] = mb[t] - a * mu;
    }
    __syncthreads();
    for (int i = t; i < G_GRAPHS * HID; i += 256) {
        int g = i >> 5, c = i & 31;
        hm[g][c] = fmaxf(fmaf(hm[g][c], sc[c], sh[c]), 0.f);
    }
    __syncthreads();
    for (int i = t; i < G_GRAPHS * NCLS; i += 256) {
        int g = i / NCLS, c = i % NCLS;
        float acc = 0.f;
        for (int k = 0; k < HID; ++k) acc = fmaf(hm[g][k], w2[k * NCLS + c], acc);
        lgt[g][c] = acc;
    }
    __syncthreads();
    if (t < G_GRAPHS) {
        float mx = -INFINITY;
        for (int c = 0; c < NCLS; ++c) mx = fmaxf(mx, lgt[t][c]);
        float s = 0.f;
        for (int c = 0; c < NCLS; ++c) s += expf(lgt[t][c] - mx);
        float lse = mx + logf(s);
        for (int c = 0; c < NCLS; ++c) out[t * NCLS + c] = lgt[t][c] - lse;
    }
}

extern "C" void kernel_launch(void* const* d_in, const int* in_sizes, int n_in,
                              void* d_out, int out_size, void* d_ws, size_t ws_size,
                              hipStream_t stream) {
    (void)in_sizes; (void)n_in; (void)out_size; (void)ws_size;
    const float* feat = (const float*)d_in[0];
    const int* src = (const int*)d_in[1];
    const int* dst = (const int*)d_in[2];
    const int* seg = (const int*)d_in[3];
    auto LP = [&](int l, int j) { return (const float*)d_in[4 + 10 * l + j]; };
    const float* mw1 = (const float*)d_in[34];
    const float* mg  = (const float*)d_in[35];
    const float* mb  = (const float*)d_in[36];
    const float* mw2 = (const float*)d_in[37];

    char* p = (char*)d_ws;
    auto alloc = [&](size_t bytes) { char* r = p; p += (bytes + 255) & ~(size_t)255; return r; };
    unsigned short* Hb = (unsigned short*)alloc((size_t)N_NODES * HDIM * 2);
    unsigned short* Yb = (unsigned short*)alloc((size_t)N_NODES * HDIM * 2);
    int*   ssrc   = (int*)alloc((size_t)N_EDGES * 4);
    unsigned int* gbuf = (unsigned int*)alloc((size_t)N_EDGES * 4);
    int*   rp     = (int*)alloc((size_t)(N_NODES + 1) * 4);
    // contiguous zero region: bcnt | statsAll | bcur  (NZ_DWORDS dwords)
    int*   bcnt   = (int*)alloc((size_t)NBUCK * 4);                 // 256 B
    float* statsAll = (float*)alloc((size_t)3 * STATS_STRIDE * 4);  // 101376 B (256-mult)
    int*   bcur   = (int*)alloc((size_t)NBUCK * 4);                 // 256 B
    float* pl_all = (float*)alloc((size_t)3 * G_GRAPHS * HID * 4);
    int*   gs     = (int*)alloc((size_t)(G_GRAPHS + 1) * 4);
    unsigned short* WL = (unsigned short*)alloc((size_t)3 * HDIM * HDIM * 2);
    float* Fb     = (float*)alloc((size_t)3 * HDIM * 4);

    // prep: layer-0 WL (blocks 0-15) + zero bcnt/stats/bcur (16-19) + graph bounds (20)
    k_prep<<<21, 256, 0, stream>>>(LP(0, 0), WL, (unsigned int*)bcnt, seg, gs);
    // bucket histogram + layer-0 GEMM, fused (independent inputs)
    k_mega0<<<NCHUNK + NGB_GEMM, 256, 0, stream>>>(dst, bcnt, WL, feat, LP(0, 1), Hb);
    k_bscatter<<<NCHUNK, 256, 0, stream>>>(dst, src, bcnt, bcur, gbuf);
    k_bsort<<<NBUCK, 256, CAP_OUT * 4, stream>>>(bcnt, gbuf, ssrc, rp);

    for (int l = 0; l < 3; ++l) {
        float* sums   = statsAll + (size_t)l * STATS_STRIDE;
        float* sumsq  = sums + 128;
        float* pooled = sums + 256;
        if (l > 0) {
            k_gemm_mfma<false><<<NGB_GEMM, 256, 0, stream>>>(
                Yb, WL + (size_t)l * HDIM * HDIM, Fb + (size_t)l * HDIM, Hb);
        }
        k_edge<<<(N_NODES + 3) / 4, 256, 0, stream>>>(Hb, rp, ssrc, LP(l, 2), LP(l, 3), Yb);
        k_stats_pool<<<NB_SCAN, 256, 0, stream>>>(Yb, seg, sums, sumsq, pooled);
        if (l < 2) {
            k_fold<<<65, 256, 0, stream>>>(sums, sumsq, LP(l, 4), LP(l, 5),
                                           LP(l + 1, 0), LP(l + 1, 1),
                                           WL + (size_t)(l + 1) * HDIM * HDIM,
                                           Fb + (size_t)(l + 1) * HDIM);
        }
    }
    // deferred heads (off the per-layer critical path)
    k_heads1<<<G_GRAPHS, 256, 0, stream>>>(statsAll, gs,
                                           LP(0, 4), LP(0, 5), LP(1, 4), LP(1, 5), LP(2, 4), LP(2, 5),
                                           LP(0, 6), LP(0, 7), LP(1, 6), LP(1, 7), LP(2, 6), LP(2, 7),
                                           pl_all);
    k_final<<<1, 256, 0, stream>>>(pl_all,
                                   LP(0, 8), LP(0, 9), LP(1, 8), LP(1, 9), LP(2, 8), LP(2, 9),
                                   mw1, mg, mb, mw2, (float*)d_out);
}

// Round 12
// 358.718 us; speedup vs baseline: 1.0106x; 1.0106x over previous
//
#include <hip/hip_runtime.h>
#include <math.h>

#define N_NODES 50000
#define N_EDGES 800000
#define G_GRAPHS 64
#define HDIM 128
#define HID 32
#define NCLS 10
#define BN_EPS 1e-5f
#define SLOPE 0.2f
#define NB_SCAN 196
#define STATS_STRIDE (256 + G_GRAPHS * HDIM)
#define DEFER_THR 8.0f

// bucket sort geometry
#define NBUCK 64
#define NPB 782              // nodes per bucket; 64*782 = 50048 >= N_NODES
#define CH 4096              // edges per scatter chunk
#define NCHUNK 196           // ceil(N_EDGES / CH)
#define NGB_GEMM 782         // gemm blocks: ceil(N_NODES/64)
#define CAP_OUT 13824        // per-bucket sort capacity (mean 12512, sigma 111)
#define NZ_DWORDS (64 + 3 * STATS_STRIDE + 64 + 64)  // bcnt | statsAll | bcur | cnts

typedef __attribute__((ext_vector_type(8))) short bf16x8;
typedef __attribute__((ext_vector_type(4))) float f32x4;

__device__ __forceinline__ float lrelu(float x) { return fmaxf(x, SLOPE * x); }

__device__ __forceinline__ unsigned short f2bf(float x) {
    unsigned int u = __float_as_uint(x);
    u = (u + 0x7fffu + ((u >> 16) & 1u)) >> 16;
    return (unsigned short)u;
}
__device__ __forceinline__ unsigned int pk2bf(float lo, float hi) {
    unsigned int r;
    asm("v_cvt_pk_bf16_f32 %0, %1, %2" : "=v"(r) : "v"(lo), "v"(hi));
    return r;
}
__device__ __forceinline__ float2 up2(unsigned int u) {
    return make_float2(__uint_as_float(u << 16), __uint_as_float(u & 0xffff0000u));
}
__device__ __forceinline__ float bf2f(unsigned short u) {
    return __uint_as_float((unsigned int)u << 16);
}
__device__ __forceinline__ int wl_index(int k, int c) {
    int lane = ((k >> 3) & 3) * 16 + (c & 15);
    return (((k >> 5) * 8 + (c >> 4)) * 64 + lane) * 8 + (k & 7);
}

// ---------------- MFMA GEMM body: Hb = bf16( X @ W' + fb' ) ----------------
template <bool XF32>
__device__ __forceinline__ void gemm_body(int bid, const void* __restrict__ Xv,
                                          const unsigned short* __restrict__ WL,
                                          const float* __restrict__ fb,
                                          unsigned short* __restrict__ Hb) {
    int t = threadIdx.x;
    int w = t >> 6, lane = t & 63;
    int i16 = lane & 15, kg = lane >> 4;
    int r0w = bid * 64 + w * 16;
    int row = r0w + i16;
    int rowc = row < N_NODES ? row : N_NODES - 1;

    f32x4 acc[8];
    #pragma unroll
    for (int cs = 0; cs < 8; ++cs) acc[cs] = (f32x4){0.f, 0.f, 0.f, 0.f};

    #pragma unroll
    for (int ks = 0; ks < 4; ++ks) {
        union { uint4 u; bf16x8 s; } af;
        if (XF32) {
            const float* xp = (const float*)Xv + (size_t)rowc * HDIM + ks * 32 + kg * 8;
            float4 v0 = *(const float4*)xp;
            float4 v1 = *(const float4*)(xp + 4);
            af.u.x = pk2bf(v0.x, v0.y);
            af.u.y = pk2bf(v0.z, v0.w);
            af.u.z = pk2bf(v1.x, v1.y);
            af.u.w = pk2bf(v1.z, v1.w);
        } else {
            const unsigned short* xp = (const unsigned short*)Xv + (size_t)rowc * HDIM + ks * 32 + kg * 8;
            af.u = *(const uint4*)xp;
        }
        #pragma unroll
        for (int cs = 0; cs < 8; ++cs) {
            union { uint4 u; bf16x8 s; } bw;
            bw.u = *(const uint4*)&WL[(((ks << 3) + cs) * 64 + lane) * 8];
            acc[cs] = __builtin_amdgcn_mfma_f32_16x16x32_bf16(af.s, bw.s, acc[cs], 0, 0, 0);
        }
    }
    #pragma unroll
    for (int cs = 0; cs < 8; ++cs) {
        int col = cs * 16 + i16;
        float bias = fb[col];
        #pragma unroll
        for (int p = 0; p < 4; ++p) {
            int r = r0w + kg * 4 + p;
            if (r < N_NODES) Hb[(size_t)r * HDIM + col] = f2bf(acc[cs][p] + bias);
        }
    }
}

template <bool XF32>
__global__ __launch_bounds__(256) void k_gemm_mfma(const void* __restrict__ Xv,
                                                   const unsigned short* __restrict__ WL,
                                                   const float* __restrict__ fb,
                                                   unsigned short* __restrict__ Hb) {
    gemm_body<XF32>(blockIdx.x, Xv, WL, fb, Hb);
}

// ---------------- prep: blocks 0..15 = layer-0 W prep; 16..19 = zero-fill; 20 = graph bounds ----------------
__global__ __launch_bounds__(256) void k_prep(const float* __restrict__ W,
                                              unsigned short* __restrict__ WL,
                                              unsigned int* __restrict__ zbase,
                                              const int* __restrict__ seg,
                                              int* __restrict__ gs) {
    int bid = blockIdx.x, t = threadIdx.x;
    if (bid < 16) {
        for (int idx = bid * 256 + t; idx < HDIM * HDIM; idx += 16 * 256) {
            int k = idx >> 7, c = idx & 127;
            WL[wl_index(k, c)] = f2bf(W[idx]);
        }
    } else if (bid < 20) {
        for (int i = (bid - 16) * 256 + t; i < NZ_DWORDS; i += 4 * 256) zbase[i] = 0u;
    } else {
        if (t <= G_GRAPHS) {
            int g = t;
            int lo = 0, hi = N_NODES;
            while (lo < hi) {
                int mid = (lo + hi) >> 1;
                if (seg[mid] < g) lo = mid + 1; else hi = mid;
            }
            gs[g] = lo;
        }
    }
}

// ---------------- mega0: bucket histogram (196) + gemm L0 (782) ----------------
__global__ __launch_bounds__(256) void k_mega0(const int* __restrict__ dst,
                                               int* __restrict__ bcnt,
                                               const unsigned short* __restrict__ WL0,
                                               const float* __restrict__ feat,
                                               const float* __restrict__ fb0,
                                               unsigned short* __restrict__ Hb) {
    __shared__ unsigned int h[NBUCK];
    int bid = blockIdx.x;
    int t = threadIdx.x;
    if (bid < NCHUNK) {
        if (t < NBUCK) h[t] = 0;
        __syncthreads();
        int base = bid * CH;
        #pragma unroll
        for (int e = 0; e < 16; ++e) {
            int i = base + e * 256 + t;
            if (i < N_EDGES) {
                int d = dst[i];
                atomicAdd(&h[d / NPB], 1u);
            }
        }
        __syncthreads();
        if (t < NBUCK && h[t]) atomicAdd(&bcnt[t], (int)h[t]);
    } else {
        gemm_body<true>(bid - NCHUNK, feat, WL0, fb0, Hb);
    }
}

// ---------------- scatter into buckets (local bbase scan; bcur is zero-based cursor) ----------------
__global__ __launch_bounds__(256) void k_bscatter(const int* __restrict__ dst,
                                                  const int* __restrict__ src,
                                                  const int* __restrict__ bcnt,
                                                  int* __restrict__ bcur,
                                                  unsigned int* __restrict__ gbuf) {
    __shared__ unsigned int hist[NBUCK];
    __shared__ unsigned int scanB[NBUCK + 1];
    __shared__ int gdelta[NBUCK];
    __shared__ unsigned int cur[NBUCK];
    __shared__ unsigned int ent[CH];
    __shared__ int bb[NBUCK];
    int t = threadIdx.x;
    int base = blockIdx.x * CH;
    unsigned int eb[16], een[16];
    if (t < NBUCK) {
        int v = bcnt[t];
        int inc = v;
        #pragma unroll
        for (int off = 1; off < 64; off <<= 1) {
            int u = __shfl_up(inc, off);
            if (t >= off) inc += u;
        }
        bb[t] = inc - v;   // exclusive global bucket base
        hist[t] = 0;
    }
    __syncthreads();
    #pragma unroll
    for (int e = 0; e < 16; ++e) {
        int i = base + e * 256 + t;
        if (i < N_EDGES) {
            int d = dst[i];
            int s = src[i];
            int b = d / NPB;
            eb[e] = (unsigned int)b;
            een[e] = ((unsigned int)(d - b * NPB) << 17) | (unsigned int)s;
            atomicAdd(&hist[b], 1u);
        } else {
            eb[e] = 0xFFFFFFFFu;
            een[e] = 0;
        }
    }
    __syncthreads();
    if (t < NBUCK) {
        unsigned int v = hist[t];
        unsigned int inc = v;
        #pragma unroll
        for (int off = 1; off < 64; off <<= 1) {
            unsigned int u = __shfl_up(inc, off);
            if ((t & 63) >= off) inc += u;
        }
        scanB[t + 1] = inc;
        if (t == 0) scanB[0] = 0;
    }
    __syncthreads();
    if (t < NBUCK) {
        unsigned int hv = hist[t];
        int gb = bb[t] + (hv ? atomicAdd(&bcur[t], (int)hv) : 0);
        gdelta[t] = gb - (int)scanB[t];
        cur[t] = 0;
    }
    __syncthreads();
    #pragma unroll
    for (int e = 0; e < 16; ++e) {
        if (eb[e] < NBUCK) {
            unsigned int pos = scanB[eb[e]] + atomicAdd(&cur[eb[e]], 1u);
            ent[pos] = een[e];
        }
    }
    __syncthreads();
    unsigned int cntE = scanB[NBUCK];
    #pragma unroll
    for (int e = 0; e < 16; ++e) {
        unsigned int i = (unsigned int)(e * 256 + t);
        if (i < cntE) {
            int lo2 = 0, hi2 = NBUCK;
            while (hi2 - lo2 > 1) {
                int mid = (lo2 + hi2) >> 1;
                if (scanB[mid] <= i) lo2 = mid; else hi2 = mid;
            }
            gbuf[gdelta[lo2] + i] = ent[i];
        }
    }
}

// ---------------- per-bucket counting sort -> ssrc + rowptr (local bbase scan) ----------------
__global__ __launch_bounds__(256) void k_bsort(const int* __restrict__ bcnt,
                                               const unsigned int* __restrict__ gbuf,
                                               int* __restrict__ ssrc,
                                               int* __restrict__ rowptr) {
    extern __shared__ unsigned int sout[];   // CAP_OUT
    __shared__ unsigned int hist[NPB];
    __shared__ unsigned int sbase[NPB + 1];
    __shared__ unsigned int cur[NPB];
    __shared__ unsigned int wsum[4];
    __shared__ int sbb[NBUCK + 1];
    int b = blockIdx.x;
    int t = threadIdx.x;
    if (t < NBUCK) {
        int v = bcnt[t];
        int inc = v;
        #pragma unroll
        for (int off = 1; off < 64; off <<= 1) {
            int u = __shfl_up(inc, off);
            if (t >= off) inc += u;
        }
        sbb[t + 1] = inc;
        if (t == 0) sbb[0] = 0;
    }
    __syncthreads();
    int lo = sbb[b], hi = sbb[b + 1];
    int cnt = hi - lo;
    if (cnt > CAP_OUT) cnt = CAP_OUT;
    for (int i = t; i < NPB; i += 256) { hist[i] = 0; cur[i] = 0; }
    __syncthreads();
    for (int i = t; i < cnt; i += 256) {
        unsigned int e = gbuf[lo + i];
        atomicAdd(&hist[e >> 17], 1u);
    }
    __syncthreads();
    unsigned int loc[4], s = 0;
    #pragma unroll
    for (int j = 0; j < 4; ++j) {
        int idx = t * 4 + j;
        loc[j] = idx < NPB ? hist[idx] : 0;
        s += loc[j];
    }
    unsigned int inc = s;
    #pragma unroll
    for (int off = 1; off < 64; off <<= 1) {
        unsigned int u = __shfl_up(inc, off);
        if ((t & 63) >= off) inc += u;
    }
    int wid = t >> 6;
    if ((t & 63) == 63) wsum[wid] = inc;
    __syncthreads();
    if (t == 0) {
        unsigned int r = 0;
        #pragma unroll
        for (int w = 0; w < 4; ++w) { unsigned int x = wsum[w]; wsum[w] = r; r += x; }
    }
    __syncthreads();
    unsigned int excl = inc - s + wsum[wid];
    #pragma unroll
    for (int j = 0; j < 4; ++j) {
        int idx = t * 4 + j;
        if (idx < NPB) { sbase[idx] = excl; excl += loc[j]; }
    }
    if (t == 255) sbase[NPB] = excl;
    __syncthreads();
    for (int v = t; v < NPB; v += 256) {
        int nid = b * NPB + v;
        if (nid < N_NODES) rowptr[nid] = lo + (int)sbase[v];
    }
    if (b == NBUCK - 1 && t == 0) rowptr[N_NODES] = N_EDGES;
    for (int i = t; i < cnt; i += 256) {
        unsigned int e = gbuf[lo + i];
        unsigned int dl = e >> 17;
        unsigned int pos = sbase[dl] + atomicAdd(&cur[dl], 1u);
        if (pos < (unsigned int)CAP_OUT) sout[pos] = e & 0x1FFFFu;
    }
    __syncthreads();
    for (int i = t; i < cnt; i += 256) ssrc[lo + i] = (int)sout[i];
}

// ---------------- fused edge kernel: 4 edge-slots/wave, dwordx4 gathers (R8 version) ----------------
__global__ __launch_bounds__(256) void k_edge(const unsigned short* __restrict__ Hb,
                                              const int* __restrict__ row_ptr,
                                              const int* __restrict__ ssrc,
                                              const float* __restrict__ attn,
                                              const float* __restrict__ ob,
                                              unsigned short* __restrict__ Yb) {
    int wid = blockIdx.x * 4 + (threadIdx.x >> 6);
    if (wid >= N_NODES) return;
    int lane = threadIdx.x & 63;
    int slot = lane >> 4, s16 = lane & 15;
    int d0 = s16 << 3;
    int beg = row_ptr[wid], end = row_ptr[wid + 1];
    int deg = end - beg;
    if (deg == 0) {
        if (slot == 0) {
            float4 o0 = *(const float4*)&ob[d0];
            float4 o1 = *(const float4*)&ob[d0 + 4];
            uint4 w;
            w.x = pk2bf(fmaxf(o0.x, 0.f), fmaxf(o0.y, 0.f));
            w.y = pk2bf(fmaxf(o0.z, 0.f), fmaxf(o0.w, 0.f));
            w.z = pk2bf(fmaxf(o1.x, 0.f), fmaxf(o1.y, 0.f));
            w.w = pk2bf(fmaxf(o1.z, 0.f), fmaxf(o1.w, 0.f));
            *(uint4*)&Yb[(size_t)wid * HDIM + d0] = w;
        }
        return;
    }
    float er[8], at[8];
    {
        uint4 e = *(const uint4*)&Hb[(size_t)wid * HDIM + d0];
        unsigned int uu[4] = {e.x, e.y, e.z, e.w};
        #pragma unroll
        for (int i = 0; i < 4; ++i) {
            float2 f = up2(uu[i]);
            er[2 * i] = f.x; er[2 * i + 1] = f.y;
        }
        float4 a0 = *(const float4*)&attn[d0];
        float4 a1 = *(const float4*)&attn[d0 + 4];
        at[0] = a0.x; at[1] = a0.y; at[2] = a0.z; at[3] = a0.w;
        at[4] = a1.x; at[5] = a1.y; at[6] = a1.z; at[7] = a1.w;
    }
    const float NINF = __int_as_float(0xff800000);
    float m = -1e30f, den = 0.f;
    float acc[8] = {0.f, 0.f, 0.f, 0.f, 0.f, 0.f, 0.f, 0.f};
    int nit = (deg + 3) >> 2;
    int j = beg + slot;
    int sa;
    uint4 elc;
    {
        int jc0 = j < end ? j : beg;
        int jc1 = (j + 4) < end ? (j + 4) : beg;
        int s0 = ssrc[jc0];
        sa = ssrc[jc1];
        elc = *(const uint4*)&Hb[(size_t)s0 * HDIM + d0];
    }
    for (int it = 0; it < nit; ++it) {
        int jc2 = (j + 8) < end ? (j + 8) : beg;
        int sb = ssrc[jc2];
        uint4 eln = *(const uint4*)&Hb[(size_t)sa * HDIM + d0];
        bool act = j < end;
        float el[8];
        {
            unsigned int uu[4] = {elc.x, elc.y, elc.z, elc.w};
            #pragma unroll
            for (int i = 0; i < 4; ++i) {
                float2 f = up2(uu[i]);
                el[2 * i] = f.x; el[2 * i + 1] = f.y;
            }
        }
        float p = 0.f;
        #pragma unroll
        for (int d = 0; d < 8; ++d) p = fmaf(lrelu(el[d] + er[d]), at[d], p);
        p += __shfl_xor(p, 1);
        p += __shfl_xor(p, 2);
        float e = act ? p : NINF;
        if (__all(e - m <= DEFER_THR)) {
            float q = __expf(e - m);
            den += q;
            #pragma unroll
            for (int d = 0; d < 8; ++d) acc[d] = fmaf(el[d], q, acc[d]);
        } else {
            float nm = fmaxf(m, e);
            float r = __expf(m - nm);
            float q = __expf(e - nm);
            den = fmaf(den, r, q);
            #pragma unroll
            for (int d = 0; d < 8; ++d) acc[d] = fmaf(acc[d], r, el[d] * q);
            m = nm;
        }
        elc = eln; sa = sb; j += 4;
    }
    #pragma unroll
    for (int st = 16; st <= 32; st <<= 1) {
        float m2 = __shfl_xor(m, st);
        float den2 = __shfl_xor(den, st);
        float nm = fmaxf(m, m2);
        float r1 = __expf(m - nm);
        float r2 = __expf(m2 - nm);
        den = den * r1 + den2 * r2;
        #pragma unroll
        for (int d = 0; d < 8; ++d) {
            float a2 = __shfl_xor(acc[d], st);
            acc[d] = acc[d] * r1 + a2 * r2;
        }
        m = nm;
    }
    if (slot == 0) {
        float inv = den > 0.f ? 1.f / den : 0.f;
        float4 o0 = *(const float4*)&ob[d0];
        float4 o1 = *(const float4*)&ob[d0 + 4];
        float o[8] = {o0.x, o0.y, o0.z, o0.w, o1.x, o1.y, o1.z, o1.w};
        float r[8];
        #pragma unroll
        for (int d = 0; d < 8; ++d) r[d] = fmaxf(fmaf(acc[d], inv, o[d]), 0.f);
        uint4 w;
        w.x = pk2bf(r[0], r[1]);
        w.y = pk2bf(r[2], r[3]);
        w.z = pk2bf(r[4], r[5]);
        w.w = pk2bf(r[6], r[7]);
        *(uint4*)&Yb[(size_t)wid * HDIM + d0] = w;
    }
}

// ---------------- fused BN stats + per-graph sum pool + last-block W-fold ----------------
__global__ __launch_bounds__(256) void k_stats_fold(const unsigned short* __restrict__ Yb,
                                                    const int* __restrict__ seg,
                                                    float* __restrict__ sums,
                                                    float* __restrict__ sumsq,
                                                    float* __restrict__ pooled,
                                                    const float* __restrict__ bng,
                                                    const float* __restrict__ bnb,
                                                    const float* __restrict__ Wnext,
                                                    const float* __restrict__ fbnext,
                                                    unsigned short* __restrict__ WLnext,
                                                    float* __restrict__ Fbnext,
                                                    int* __restrict__ counter) {
    __shared__ float4 red[256];
    __shared__ int sseg[256];
    __shared__ float sA[HDIM], sB[HDIM];
    __shared__ unsigned int lastFlag;
    int t = threadIdx.x;
    int r0 = blockIdx.x * 256;
    if (r0 + t < N_NODES) sseg[t] = seg[r0 + t];
    __syncthreads();
    int c4 = t & 31, rh = t >> 5;
    int rend = r0 + 256 < N_NODES ? r0 + 256 : N_NODES;
    float sx = 0.f, sy = 0.f, sz = 0.f, sw = 0.f;
    float qx = 0.f, qy = 0.f, qz = 0.f, qw = 0.f;
    int curg = -1;
    float rx = 0.f, ry = 0.f, rz = 0.f, rw = 0.f;
    for (int r = r0 + rh; r < rend; r += 8) {
        ushort4 v = *(const ushort4*)&Yb[(size_t)r * HDIM + c4 * 4];
        float x0 = bf2f(v.x), x1 = bf2f(v.y), x2 = bf2f(v.z), x3 = bf2f(v.w);
        sx += x0; sy += x1; sz += x2; sw += x3;
        qx = fmaf(x0, x0, qx); qy = fmaf(x1, x1, qy);
        qz = fmaf(x2, x2, qz); qw = fmaf(x3, x3, qw);
        int g = sseg[r - r0];
        if (g != curg) {
            if (curg >= 0) {
                float* pp = &pooled[curg * HDIM + c4 * 4];
                atomicAdd(pp + 0, rx); atomicAdd(pp + 1, ry);
                atomicAdd(pp + 2, rz); atomicAdd(pp + 3, rw);
            }
            curg = g;
            rx = x0; ry = x1; rz = x2; rw = x3;
        } else {
            rx += x0; ry += x1; rz += x2; rw += x3;
        }
    }
    if (curg >= 0) {
        float* pp = &pooled[curg * HDIM + c4 * 4];
        atomicAdd(pp + 0, rx); atomicAdd(pp + 1, ry);
        atomicAdd(pp + 2, rz); atomicAdd(pp + 3, rw);
    }
    red[t] = make_float4(sx, sy, sz, sw);
    __syncthreads();
    if (rh == 0) {
        float4 tot = red[c4];
        #pragma unroll
        for (int i = 1; i < 8; ++i) {
            float4 o = red[i * 32 + c4];
            tot.x += o.x; tot.y += o.y; tot.z += o.z; tot.w += o.w;
        }
        float* sp = &sums[c4 * 4];
        atomicAdd(sp + 0, tot.x); atomicAdd(sp + 1, tot.y);
        atomicAdd(sp + 2, tot.z); atomicAdd(sp + 3, tot.w);
    }
    __syncthreads();
    red[t] = make_float4(qx, qy, qz, qw);
    __syncthreads();
    if (rh == 0) {
        float4 tot = red[c4];
        #pragma unroll
        for (int i = 1; i < 8; ++i) {
            float4 o = red[i * 32 + c4];
            tot.x += o.x; tot.y += o.y; tot.z += o.z; tot.w += o.w;
        }
        float* sp = &sumsq[c4 * 4];
        atomicAdd(sp + 0, tot.x); atomicAdd(sp + 1, tot.y);
        atomicAdd(sp + 2, tot.z); atomicAdd(sp + 3, tot.w);
    }
    if (!Wnext) return;
    // last-block epilogue: fold BN into next layer's weights (replaces k_fold dispatch)
    __threadfence();
    if (t == 0) lastFlag = (atomicAdd(counter, 1) == NB_SCAN - 1) ? 1u : 0u;
    __syncthreads();
    if (!lastFlag) return;
    __threadfence();
    if (t < HDIM) {
        float sv = atomicAdd(&sums[t], 0.f);     // coherent read of atomically-built value
        float qv = atomicAdd(&sumsq[t], 0.f);
        float mu = sv * (1.f / N_NODES);
        float var = fmaxf(qv * (1.f / N_NODES) - mu * mu, 0.f);
        float inv = rsqrtf(var + BN_EPS);
        float a = bng[t] * inv;
        sA[t] = a;
        sB[t] = bnb[t] - a * mu;
    }
    __syncthreads();
    for (int idx = t; idx < HDIM * HDIM; idx += 256) {
        int k = idx >> 7, c = idx & 127;
        WLnext[wl_index(k, c)] = f2bf(sA[k] * Wnext[idx]);
    }
    if (t < HDIM) {
        float a = fbnext[t];
        for (int k = 0; k < HDIM; ++k) a = fmaf(sB[k], Wnext[k * HDIM + t], a);
        Fbnext[t] = a;
    }
}

// ---------------- heads (one block per graph, all 3 layers) + last-block final MLP ----------------
__global__ __launch_bounds__(256) void k_headsfinal(const float* __restrict__ statsAll,
                                                    const int* __restrict__ gs,
                                                    const float* __restrict__ bng0, const float* __restrict__ bnb0,
                                                    const float* __restrict__ bng1, const float* __restrict__ bnb1,
                                                    const float* __restrict__ bng2, const float* __restrict__ bnb2,
                                                    const float* __restrict__ lw0, const float* __restrict__ lb0,
                                                    const float* __restrict__ lw1, const float* __restrict__ lb1,
                                                    const float* __restrict__ lw2, const float* __restrict__ lb2,
                                                    float* __restrict__ pl_all,
                                                    const float* __restrict__ lg0, const float* __restrict__ lbt0,
                                                    const float* __restrict__ lg1, const float* __restrict__ lbt1,
                                                    const float* __restrict__ lg2, const float* __restrict__ lbt2,
                                                    const float* __restrict__ mw1,
                                                    const float* __restrict__ mg,
                                                    const float* __restrict__ mb,
                                                    const float* __restrict__ mw2,
                                                    float* __restrict__ out,
                                                    int* __restrict__ counter) {
    __shared__ float sA3[3][HDIM], sB3[3][HDIM];
    __shared__ float red[8][HID];
    __shared__ unsigned int lastFlag;
    int g = blockIdx.x, t = threadIdx.x;
    const float* bngs[3] = {bng0, bng1, bng2};
    const float* bnbs[3] = {bnb0, bnb1, bnb2};
    const float* lws[3] = {lw0, lw1, lw2};
    const float* lbs[3] = {lb0, lb1, lb2};
    if (t < HDIM) {
        #pragma unroll
        for (int l = 0; l < 3; ++l) {
            const float* su = statsAll + (size_t)l * STATS_STRIDE;
            float mu = su[t] * (1.f / N_NODES);
            float var = fmaxf(su[128 + t] * (1.f / N_NODES) - mu * mu, 0.f);
            float inv = rsqrtf(var + BN_EPS);
            float a = bngs[l][t] * inv;
            sA3[l][t] = a;
            sB3[l][t] = bnbs[l][t] - a * mu;
        }
    }
    __syncthreads();
    float cntg = (float)(gs[g + 1] - gs[g]);
    int col = t & 31, kq = t >> 5;
    #pragma unroll
    for (int l = 0; l < 3; ++l) {
        const float* pg = statsAll + (size_t)l * STATS_STRIDE + 256 + (size_t)g * HDIM;
        float part = 0.f;
        #pragma unroll
        for (int kk = 0; kk < 16; ++kk) {
            int k = kq * 16 + kk;
            float pin = fmaf(sA3[l][k], pg[k], cntg * sB3[l][k]);
            part = fmaf(pin, lws[l][k * HID + col], part);
        }
        red[kq][col] = part;
        __syncthreads();
        if (kq == 0) {
            float s = red[0][col] + red[1][col] + red[2][col] + red[3][col]
                    + red[4][col] + red[5][col] + red[6][col] + red[7][col];
            pl_all[((size_t)l * G_GRAPHS + g) * HID + col] = fmaxf(s + lbs[l][col], 0.f);
        }
        __syncthreads();
    }
    // last-block final head
    __threadfence();
    if (t == 0) lastFlag = (atomicAdd(counter, 1) == G_GRAPHS - 1) ? 1u : 0u;
    __syncthreads();
    if (!lastFlag) return;
    __threadfence();
    {
        __shared__ float pl3[3 * G_GRAPHS * HID];   // 24 KB
        __shared__ float w1[3 * HID * HID];         // 12 KB
        __shared__ float hm[G_GRAPHS][HID];         // 8 KB
        __shared__ float sc[96], sh[96];
        __shared__ float lgt[G_GRAPHS][NCLS];
        __shared__ float w2[HID * NCLS];
        const float* lgs[3] = {lg0, lg1, lg2};
        const float* lbts[3] = {lbt0, lbt1, lbt2};
        for (int i = t; i < 3 * G_GRAPHS * HID; i += 256) pl3[i] = pl_all[i];
        for (int i = t; i < 3 * HID * HID; i += 256) w1[i] = mw1[i];
        for (int i = t; i < HID * NCLS; i += 256) w2[i] = mw2[i];
        __syncthreads();
        if (t < 96) {
            int l = t >> 5, c = t & 31;
            float s = 0.f, q = 0.f;
            for (int gg = 0; gg < G_GRAPHS; ++gg) {
                float v = pl3[(l * G_GRAPHS + gg) * HID + c];
                s += v; q = fmaf(v, v, q);
            }
            float mu = s * (1.f / G_GRAPHS);
            float var = fmaxf(q * (1.f / G_GRAPHS) - mu * mu, 0.f);
            float inv = rsqrtf(var + BN_EPS);
            float a = lgs[l][c] * inv;
            sc[t] = a;
            sh[t] = lbts[l][c] - a * mu;
        }
        __syncthreads();
        for (int i = t; i < 3 * G_GRAPHS * HID; i += 256) {
            int l = i / (G_GRAPHS * HID);
            int c = i & 31;
            pl3[i] = fmaf(pl3[i], sc[l * 32 + c], sh[l * 32 + c]);
        }
        __syncthreads();
        for (int i = t; i < G_GRAPHS * HID; i += 256) {
            int gg = i >> 5, c = i & 31;
            float acc = 0.f;
            #pragma unroll
            for (int l = 0; l < 3; ++l)
                for (int k = 0; k < HID; ++k)
                    acc = fmaf(pl3[(l * G_GRAPHS + gg) * HID + k], w1[(l * HID + k) * HID + c], acc);
            hm[gg][c] = acc;
        }
        __syncthreads();
        if (t < HID) {
            float s = 0.f, q = 0.f;
            for (int gg = 0; gg < G_GRAPHS; ++gg) {
                float v = hm[gg][t];
                s += v; q = fmaf(v, v, q);
            }
            float mu = s * (1.f / G_GRAPHS);
            float var = fmaxf(q * (1.f / G_GRAPHS) - mu * mu, 0.f);
            float inv = rsqrtf(var + BN_EPS);
            float a = mg[t] * inv;
            sc[t] = a;
            sh[t] = mb[t] - a * mu;
        }
        __syncthreads();
        for (int i = t; i < G_GRAPHS * HID; i += 256) {
            int gg = i >> 5, c = i & 31;
            hm[gg][c] = fmaxf(fmaf(hm[gg][c], sc[c], sh[c]), 0.f);
        }
        __syncthreads();
        for (int i = t; i < G_GRAPHS * NCLS; i += 256) {
            int gg = i / NCLS, c = i % NCLS;
            float acc = 0.f;
            for (int k = 0; k < HID; ++k) acc = fmaf(hm[gg][k], w2[k * NCLS + c], acc);
            lgt[gg][c] = acc;
        }
        __syncthreads();
        if (t < G_GRAPHS) {
            float mx = -INFINITY;
            for (int c = 0; c < NCLS; ++c) mx = fmaxf(mx, lgt[t][c]);
            float s = 0.f;
            for (int c = 0; c < NCLS; ++c) s += expf(lgt[t][c] - mx);
            float lse = mx + logf(s);
            for (int c = 0; c < NCLS; ++c) out[t * NCLS + c] = lgt[t][c] - lse;
        }
    }
}

extern "C" void kernel_launch(void* const* d_in, const int* in_sizes, int n_in,
                              void* d_out, int out_size, void* d_ws, size_t ws_size,
                              hipStream_t stream) {
    (void)in_sizes; (void)n_in; (void)out_size; (void)ws_size;
    const float* feat = (const float*)d_in[0];
    const int* src = (const int*)d_in[1];
    const int* dst = (const int*)d_in[2];
    const int* seg = (const int*)d_in[3];
    auto LP = [&](int l, int j) { return (const float*)d_in[4 + 10 * l + j]; };
    const float* mw1 = (const float*)d_in[34];
    const float* mg  = (const float*)d_in[35];
    const float* mb  = (const float*)d_in[36];
    const float* mw2 = (const float*)d_in[37];

    char* p = (char*)d_ws;
    auto alloc = [&](size_t bytes) { char* r = p; p += (bytes + 255) & ~(size_t)255; return r; };
    unsigned short* Hb = (unsigned short*)alloc((size_t)N_NODES * HDIM * 2);
    unsigned short* Yb = (unsigned short*)alloc((size_t)N_NODES * HDIM * 2);
    int*   ssrc   = (int*)alloc((size_t)N_EDGES * 4);
    unsigned int* gbuf = (unsigned int*)alloc((size_t)N_EDGES * 4);
    int*   rp     = (int*)alloc((size_t)(N_NODES + 1) * 4);
    // contiguous zero region: bcnt | statsAll | bcur | cnts
    int*   bcnt   = (int*)alloc((size_t)NBUCK * 4);                 // 256 B
    float* statsAll = (float*)alloc((size_t)3 * STATS_STRIDE * 4);  // 101376 B (256-mult)
    int*   bcur   = (int*)alloc((size_t)NBUCK * 4);                 // 256 B
    int*   cnts   = (int*)alloc((size_t)64 * 4);                    // 256 B
    float* pl_all = (float*)alloc((size_t)3 * G_GRAPHS * HID * 4);
    int*   gs     = (int*)alloc((size_t)(G_GRAPHS + 1) * 4);
    unsigned short* WL = (unsigned short*)alloc((size_t)3 * HDIM * HDIM * 2);
    float* Fb     = (float*)alloc((size_t)3 * HDIM * 4);

    // prep: layer-0 WL (blocks 0-15) + zero bcnt/stats/bcur/cnts (16-19) + graph bounds (20)
    k_prep<<<21, 256, 0, stream>>>(LP(0, 0), WL, (unsigned int*)bcnt, seg, gs);
    // bucket histogram + layer-0 GEMM, fused (independent inputs)
    k_mega0<<<NCHUNK + NGB_GEMM, 256, 0, stream>>>(dst, bcnt, WL, feat, LP(0, 1), Hb);
    k_bscatter<<<NCHUNK, 256, 0, stream>>>(dst, src, bcnt, bcur, gbuf);
    k_bsort<<<NBUCK, 256, CAP_OUT * 4, stream>>>(bcnt, gbuf, ssrc, rp);

    for (int l = 0; l < 3; ++l) {
        float* sums   = statsAll + (size_t)l * STATS_STRIDE;
        float* sumsq  = sums + 128;
        float* pooled = sums + 256;
        if (l > 0) {
            k_gemm_mfma<false><<<NGB_GEMM, 256, 0, stream>>>(
                Yb, WL + (size_t)l * HDIM * HDIM, Fb + (size_t)l * HDIM, Hb);
        }
        k_edge<<<(N_NODES + 3) / 4, 256, 0, stream>>>(Hb, rp, ssrc, LP(l, 2), LP(l, 3), Yb);
        int isLast = (l == 2);
        k_stats_fold<<<NB_SCAN, 256, 0, stream>>>(
            Yb, seg, sums, sumsq, pooled, LP(l, 4), LP(l, 5),
            isLast ? nullptr : LP(l + 1, 0), isLast ? nullptr : LP(l + 1, 1),
            isLast ? nullptr : WL + (size_t)(l + 1) * HDIM * HDIM,
            isLast ? nullptr : Fb + (size_t)(l + 1) * HDIM,
            cnts + l);
    }
    // heads (64 blocks) + last-block final MLP + log_softmax
    k_headsfinal<<<G_GRAPHS, 256, 0, stream>>>(
        statsAll, gs,
        LP(0, 4), LP(0, 5), LP(1, 4), LP(1, 5), LP(2, 4), LP(2, 5),
        LP(0, 6), LP(0, 7), LP(1, 6), LP(1, 7), LP(2, 6), LP(2, 7),
        pl_all,
        LP(0, 8), LP(0, 9), LP(1, 8), LP(1, 9), LP(2, 8), LP(2, 9),
        mw1, mg, mb, mw2, (float*)d_out, cnts + 3);
}

// Round 13
// 320.189 us; speedup vs baseline: 1.1323x; 1.1203x over previous
//
#include <hip/hip_runtime.h>
#include <math.h>

#define N_NODES 50000
#define N_EDGES 800000
#define G_GRAPHS 64
#define HDIM 128
#define HID 32
#define NCLS 10
#define BN_EPS 1e-5f
#define SLOPE 0.2f
#define NB_SCAN 196
#define STATS_STRIDE (256 + G_GRAPHS * HDIM)
#define DEFER_THR 8.0f

// bucket sort geometry
#define NBUCK 64
#define NPB 782              // nodes per bucket; 64*782 = 50048 >= N_NODES
#define CH 4096              // edges per scatter chunk
#define NCHUNK 196           // ceil(N_EDGES / CH)
#define NGB_GEMM 782         // gemm blocks: ceil(N_NODES/64)
#define CAP_OUT 13824        // per-bucket sort capacity (mean 12512, sigma 111)
#define NZ_DWORDS (64 + 3 * STATS_STRIDE + 64)   // bcnt | statsAll | bcur

typedef __attribute__((ext_vector_type(8))) short bf16x8;
typedef __attribute__((ext_vector_type(4))) float f32x4;

__device__ __forceinline__ float lrelu(float x) { return fmaxf(x, SLOPE * x); }

__device__ __forceinline__ unsigned short f2bf(float x) {
    unsigned int u = __float_as_uint(x);
    u = (u + 0x7fffu + ((u >> 16) & 1u)) >> 16;
    return (unsigned short)u;
}
__device__ __forceinline__ unsigned int pk2bf(float lo, float hi) {
    unsigned int r;
    asm("v_cvt_pk_bf16_f32 %0, %1, %2" : "=v"(r) : "v"(lo), "v"(hi));
    return r;
}
__device__ __forceinline__ float2 up2(unsigned int u) {
    return make_float2(__uint_as_float(u << 16), __uint_as_float(u & 0xffff0000u));
}
__device__ __forceinline__ float bf2f(unsigned short u) {
    return __uint_as_float((unsigned int)u << 16);
}
__device__ __forceinline__ int wl_index(int k, int c) {
    int lane = ((k >> 3) & 3) * 16 + (c & 15);
    return (((k >> 5) * 8 + (c >> 4)) * 64 + lane) * 8 + (k & 7);
}

// ---------------- MFMA GEMM body: Hb = bf16( X @ W' + fb' ) ----------------
template <bool XF32>
__device__ __forceinline__ void gemm_body(int bid, const void* __restrict__ Xv,
                                          const unsigned short* __restrict__ WL,
                                          const float* __restrict__ fb,
                                          unsigned short* __restrict__ Hb) {
    int t = threadIdx.x;
    int w = t >> 6, lane = t & 63;
    int i16 = lane & 15, kg = lane >> 4;
    int r0w = bid * 64 + w * 16;
    int row = r0w + i16;
    int rowc = row < N_NODES ? row : N_NODES - 1;

    f32x4 acc[8];
    #pragma unroll
    for (int cs = 0; cs < 8; ++cs) acc[cs] = (f32x4){0.f, 0.f, 0.f, 0.f};

    #pragma unroll
    for (int ks = 0; ks < 4; ++ks) {
        union { uint4 u; bf16x8 s; } af;
        if (XF32) {
            const float* xp = (const float*)Xv + (size_t)rowc * HDIM + ks * 32 + kg * 8;
            float4 v0 = *(const float4*)xp;
            float4 v1 = *(const float4*)(xp + 4);
            af.u.x = pk2bf(v0.x, v0.y);
            af.u.y = pk2bf(v0.z, v0.w);
            af.u.z = pk2bf(v1.x, v1.y);
            af.u.w = pk2bf(v1.z, v1.w);
        } else {
            const unsigned short* xp = (const unsigned short*)Xv + (size_t)rowc * HDIM + ks * 32 + kg * 8;
            af.u = *(const uint4*)xp;
        }
        #pragma unroll
        for (int cs = 0; cs < 8; ++cs) {
            union { uint4 u; bf16x8 s; } bw;
            bw.u = *(const uint4*)&WL[(((ks << 3) + cs) * 64 + lane) * 8];
            acc[cs] = __builtin_amdgcn_mfma_f32_16x16x32_bf16(af.s, bw.s, acc[cs], 0, 0, 0);
        }
    }
    #pragma unroll
    for (int cs = 0; cs < 8; ++cs) {
        int col = cs * 16 + i16;
        float bias = fb[col];
        #pragma unroll
        for (int p = 0; p < 4; ++p) {
            int r = r0w + kg * 4 + p;
            if (r < N_NODES) Hb[(size_t)r * HDIM + col] = f2bf(acc[cs][p] + bias);
        }
    }
}

template <bool XF32>
__global__ __launch_bounds__(256) void k_gemm_mfma(const void* __restrict__ Xv,
                                                   const unsigned short* __restrict__ WL,
                                                   const float* __restrict__ fb,
                                                   unsigned short* __restrict__ Hb) {
    gemm_body<XF32>(blockIdx.x, Xv, WL, fb, Hb);
}

// ---------------- prep: blocks 0..15 = layer-0 W prep; 16..19 = zero-fill; 20 = graph bounds ----------------
__global__ __launch_bounds__(256) void k_prep(const float* __restrict__ W,
                                              unsigned short* __restrict__ WL,
                                              unsigned int* __restrict__ zbase,
                                              const int* __restrict__ seg,
                                              int* __restrict__ gs) {
    int bid = blockIdx.x, t = threadIdx.x;
    if (bid < 16) {
        for (int idx = bid * 256 + t; idx < HDIM * HDIM; idx += 16 * 256) {
            int k = idx >> 7, c = idx & 127;
            WL[wl_index(k, c)] = f2bf(W[idx]);
        }
    } else if (bid < 20) {
        for (int i = (bid - 16) * 256 + t; i < NZ_DWORDS; i += 4 * 256) zbase[i] = 0u;
    } else {
        if (t <= G_GRAPHS) {
            int g = t;
            int lo = 0, hi = N_NODES;
            while (lo < hi) {
                int mid = (lo + hi) >> 1;
                if (seg[mid] < g) lo = mid + 1; else hi = mid;
            }
            gs[g] = lo;
        }
    }
}

// ---------------- mega0: bucket histogram (196) + gemm L0 (782) ----------------
__global__ __launch_bounds__(256) void k_mega0(const int* __restrict__ dst,
                                               int* __restrict__ bcnt,
                                               const unsigned short* __restrict__ WL0,
                                               const float* __restrict__ feat,
                                               const float* __restrict__ fb0,
                                               unsigned short* __restrict__ Hb) {
    __shared__ unsigned int h[NBUCK];
    int bid = blockIdx.x;
    int t = threadIdx.x;
    if (bid < NCHUNK) {
        if (t < NBUCK) h[t] = 0;
        __syncthreads();
        int base = bid * CH;
        #pragma unroll
        for (int e = 0; e < 16; ++e) {
            int i = base + e * 256 + t;
            if (i < N_EDGES) {
                int d = dst[i];
                atomicAdd(&h[d / NPB], 1u);
            }
        }
        __syncthreads();
        if (t < NBUCK && h[t]) atomicAdd(&bcnt[t], (int)h[t]);
    } else {
        gemm_body<true>(bid - NCHUNK, feat, WL0, fb0, Hb);
    }
}

// ---------------- scatter into buckets (local bbase scan; bcur is zero-based cursor) ----------------
__global__ __launch_bounds__(256) void k_bscatter(const int* __restrict__ dst,
                                                  const int* __restrict__ src,
                                                  const int* __restrict__ bcnt,
                                                  int* __restrict__ bcur,
                                                  unsigned int* __restrict__ gbuf) {
    __shared__ unsigned int hist[NBUCK];
    __shared__ unsigned int scanB[NBUCK + 1];
    __shared__ int gdelta[NBUCK];
    __shared__ unsigned int cur[NBUCK];
    __shared__ unsigned int ent[CH];
    __shared__ int bb[NBUCK];
    int t = threadIdx.x;
    int base = blockIdx.x * CH;
    unsigned int eb[16], een[16];
    if (t < NBUCK) {
        int v = bcnt[t];
        int inc = v;
        #pragma unroll
        for (int off = 1; off < 64; off <<= 1) {
            int u = __shfl_up(inc, off);
            if (t >= off) inc += u;
        }
        bb[t] = inc - v;   // exclusive global bucket base
        hist[t] = 0;
    }
    __syncthreads();
    #pragma unroll
    for (int e = 0; e < 16; ++e) {
        int i = base + e * 256 + t;
        if (i < N_EDGES) {
            int d = dst[i];
            int s = src[i];
            int b = d / NPB;
            eb[e] = (unsigned int)b;
            een[e] = ((unsigned int)(d - b * NPB) << 17) | (unsigned int)s;
            atomicAdd(&hist[b], 1u);
        } else {
            eb[e] = 0xFFFFFFFFu;
            een[e] = 0;
        }
    }
    __syncthreads();
    if (t < NBUCK) {
        unsigned int v = hist[t];
        unsigned int inc = v;
        #pragma unroll
        for (int off = 1; off < 64; off <<= 1) {
            unsigned int u = __shfl_up(inc, off);
            if ((t & 63) >= off) inc += u;
        }
        scanB[t + 1] = inc;
        if (t == 0) scanB[0] = 0;
    }
    __syncthreads();
    if (t < NBUCK) {
        unsigned int hv = hist[t];
        int gb = bb[t] + (hv ? atomicAdd(&bcur[t], (int)hv) : 0);
        gdelta[t] = gb - (int)scanB[t];
        cur[t] = 0;
    }
    __syncthreads();
    #pragma unroll
    for (int e = 0; e < 16; ++e) {
        if (eb[e] < NBUCK) {
            unsigned int pos = scanB[eb[e]] + atomicAdd(&cur[eb[e]], 1u);
            ent[pos] = een[e];
        }
    }
    __syncthreads();
    unsigned int cntE = scanB[NBUCK];
    #pragma unroll
    for (int e = 0; e < 16; ++e) {
        unsigned int i = (unsigned int)(e * 256 + t);
        if (i < cntE) {
            int lo2 = 0, hi2 = NBUCK;
            while (hi2 - lo2 > 1) {
                int mid = (lo2 + hi2) >> 1;
                if (scanB[mid] <= i) lo2 = mid; else hi2 = mid;
            }
            gbuf[gdelta[lo2] + i] = ent[i];
        }
    }
}

// ---------------- per-bucket counting sort -> ssrc + rowptr (local bbase scan) ----------------
__global__ __launch_bounds__(256) void k_bsort(const int* __restrict__ bcnt,
                                               const unsigned int* __restrict__ gbuf,
                                               int* __restrict__ ssrc,
                                               int* __restrict__ rowptr) {
    extern __shared__ unsigned int sout[];   // CAP_OUT
    __shared__ unsigned int hist[NPB];
    __shared__ unsigned int sbase[NPB + 1];
    __shared__ unsigned int cur[NPB];
    __shared__ unsigned int wsum[4];
    __shared__ int sbb[NBUCK + 1];
    int b = blockIdx.x;
    int t = threadIdx.x;
    if (t < NBUCK) {
        int v = bcnt[t];
        int inc = v;
        #pragma unroll
        for (int off = 1; off < 64; off <<= 1) {
            int u = __shfl_up(inc, off);
            if (t >= off) inc += u;
        }
        sbb[t + 1] = inc;
        if (t == 0) sbb[0] = 0;
    }
    __syncthreads();
    int lo = sbb[b], hi = sbb[b + 1];
    int cnt = hi - lo;
    if (cnt > CAP_OUT) cnt = CAP_OUT;
    for (int i = t; i < NPB; i += 256) { hist[i] = 0; cur[i] = 0; }
    __syncthreads();
    for (int i = t; i < cnt; i += 256) {
        unsigned int e = gbuf[lo + i];
        atomicAdd(&hist[e >> 17], 1u);
    }
    __syncthreads();
    unsigned int loc[4], s = 0;
    #pragma unroll
    for (int j = 0; j < 4; ++j) {
        int idx = t * 4 + j;
        loc[j] = idx < NPB ? hist[idx] : 0;
        s += loc[j];
    }
    unsigned int inc = s;
    #pragma unroll
    for (int off = 1; off < 64; off <<= 1) {
        unsigned int u = __shfl_up(inc, off);
        if ((t & 63) >= off) inc += u;
    }
    int wid = t >> 6;
    if ((t & 63) == 63) wsum[wid] = inc;
    __syncthreads();
    if (t == 0) {
        unsigned int r = 0;
        #pragma unroll
        for (int w = 0; w < 4; ++w) { unsigned int x = wsum[w]; wsum[w] = r; r += x; }
    }
    __syncthreads();
    unsigned int excl = inc - s + wsum[wid];
    #pragma unroll
    for (int j = 0; j < 4; ++j) {
        int idx = t * 4 + j;
        if (idx < NPB) { sbase[idx] = excl; excl += loc[j]; }
    }
    if (t == 255) sbase[NPB] = excl;
    __syncthreads();
    for (int v = t; v < NPB; v += 256) {
        int nid = b * NPB + v;
        if (nid < N_NODES) rowptr[nid] = lo + (int)sbase[v];
    }
    if (b == NBUCK - 1 && t == 0) rowptr[N_NODES] = N_EDGES;
    for (int i = t; i < cnt; i += 256) {
        unsigned int e = gbuf[lo + i];
        unsigned int dl = e >> 17;
        unsigned int pos = sbase[dl] + atomicAdd(&cur[dl], 1u);
        if (pos < (unsigned int)CAP_OUT) sout[pos] = e & 0x1FFFFu;
    }
    __syncthreads();
    for (int i = t; i < cnt; i += 256) ssrc[lo + i] = (int)sout[i];
}

// ---------------- fused edge kernel: 4 edge-slots/wave, dwordx4 gathers (R8 version) ----------------
__global__ __launch_bounds__(256) void k_edge(const unsigned short* __restrict__ Hb,
                                              const int* __restrict__ row_ptr,
                                              const int* __restrict__ ssrc,
                                              const float* __restrict__ attn,
                                              const float* __restrict__ ob,
                                              unsigned short* __restrict__ Yb) {
    int wid = blockIdx.x * 4 + (threadIdx.x >> 6);
    if (wid >= N_NODES) return;
    int lane = threadIdx.x & 63;
    int slot = lane >> 4, s16 = lane & 15;
    int d0 = s16 << 3;
    int beg = row_ptr[wid], end = row_ptr[wid + 1];
    int deg = end - beg;
    if (deg == 0) {
        if (slot == 0) {
            float4 o0 = *(const float4*)&ob[d0];
            float4 o1 = *(const float4*)&ob[d0 + 4];
            uint4 w;
            w.x = pk2bf(fmaxf(o0.x, 0.f), fmaxf(o0.y, 0.f));
            w.y = pk2bf(fmaxf(o0.z, 0.f), fmaxf(o0.w, 0.f));
            w.z = pk2bf(fmaxf(o1.x, 0.f), fmaxf(o1.y, 0.f));
            w.w = pk2bf(fmaxf(o1.z, 0.f), fmaxf(o1.w, 0.f));
            *(uint4*)&Yb[(size_t)wid * HDIM + d0] = w;
        }
        return;
    }
    float er[8], at[8];
    {
        uint4 e = *(const uint4*)&Hb[(size_t)wid * HDIM + d0];
        unsigned int uu[4] = {e.x, e.y, e.z, e.w};
        #pragma unroll
        for (int i = 0; i < 4; ++i) {
            float2 f = up2(uu[i]);
            er[2 * i] = f.x; er[2 * i + 1] = f.y;
        }
        float4 a0 = *(const float4*)&attn[d0];
        float4 a1 = *(const float4*)&attn[d0 + 4];
        at[0] = a0.x; at[1] = a0.y; at[2] = a0.z; at[3] = a0.w;
        at[4] = a1.x; at[5] = a1.y; at[6] = a1.z; at[7] = a1.w;
    }
    const float NINF = __int_as_float(0xff800000);
    float m = -1e30f, den = 0.f;
    float acc[8] = {0.f, 0.f, 0.f, 0.f, 0.f, 0.f, 0.f, 0.f};
    int nit = (deg + 3) >> 2;
    int j = beg + slot;
    int sa;
    uint4 elc;
    {
        int jc0 = j < end ? j : beg;
        int jc1 = (j + 4) < end ? (j + 4) : beg;
        int s0 = ssrc[jc0];
        sa = ssrc[jc1];
        elc = *(const uint4*)&Hb[(size_t)s0 * HDIM + d0];
    }
    for (int it = 0; it < nit; ++it) {
        int jc2 = (j + 8) < end ? (j + 8) : beg;
        int sb = ssrc[jc2];
        uint4 eln = *(const uint4*)&Hb[(size_t)sa * HDIM + d0];
        bool act = j < end;
        float el[8];
        {
            unsigned int uu[4] = {elc.x, elc.y, elc.z, elc.w};
            #pragma unroll
            for (int i = 0; i < 4; ++i) {
                float2 f = up2(uu[i]);
                el[2 * i] = f.x; el[2 * i + 1] = f.y;
            }
        }
        float p = 0.f;
        #pragma unroll
        for (int d = 0; d < 8; ++d) p = fmaf(lrelu(el[d] + er[d]), at[d], p);
        p += __shfl_xor(p, 1);
        p += __shfl_xor(p, 2);
        float e = act ? p : NINF;
        if (__all(e - m <= DEFER_THR)) {
            float q = __expf(e - m);
            den += q;
            #pragma unroll
            for (int d = 0; d < 8; ++d) acc[d] = fmaf(el[d], q, acc[d]);
        } else {
            float nm = fmaxf(m, e);
            float r = __expf(m - nm);
            float q = __expf(e - nm);
            den = fmaf(den, r, q);
            #pragma unroll
            for (int d = 0; d < 8; ++d) acc[d] = fmaf(acc[d], r, el[d] * q);
            m = nm;
        }
        elc = eln; sa = sb; j += 4;
    }
    #pragma unroll
    for (int st = 16; st <= 32; st <<= 1) {
        float m2 = __shfl_xor(m, st);
        float den2 = __shfl_xor(den, st);
        float nm = fmaxf(m, m2);
        float r1 = __expf(m - nm);
        float r2 = __expf(m2 - nm);
        den = den * r1 + den2 * r2;
        #pragma unroll
        for (int d = 0; d < 8; ++d) {
            float a2 = __shfl_xor(acc[d], st);
            acc[d] = acc[d] * r1 + a2 * r2;
        }
        m = nm;
    }
    if (slot == 0) {
        float inv = den > 0.f ? 1.f / den : 0.f;
        float4 o0 = *(const float4*)&ob[d0];
        float4 o1 = *(const float4*)&ob[d0 + 4];
        float o[8] = {o0.x, o0.y, o0.z, o0.w, o1.x, o1.y, o1.z, o1.w};
        float r[8];
        #pragma unroll
        for (int d = 0; d < 8; ++d) r[d] = fmaxf(fmaf(acc[d], inv, o[d]), 0.f);
        uint4 w;
        w.x = pk2bf(r[0], r[1]);
        w.y = pk2bf(r[2], r[3]);
        w.z = pk2bf(r[4], r[5]);
        w.w = pk2bf(r[6], r[7]);
        *(uint4*)&Yb[(size_t)wid * HDIM + d0] = w;
    }
}

// ---------------- fused BN stats + per-graph sum pool (uint4 loads: 8 ch/thread) ----------------
__global__ __launch_bounds__(256) void k_stats_pool(const unsigned short* __restrict__ Yb,
                                                    const int* __restrict__ seg,
                                                    float* __restrict__ sums,
                                                    float* __restrict__ sumsq,
                                                    float* __restrict__ pooled) {
    __shared__ float red[256][8];   // 8 KB
    __shared__ int sseg[256];
    int t = threadIdx.x;
    int r0 = blockIdx.x * 256;
    if (r0 + t < N_NODES) sseg[t] = seg[r0 + t];
    __syncthreads();
    int c16 = t & 15, rh = t >> 4;   // 8 channels per thread (c16*8..+7), 16-way row split
    int cb = c16 << 3;
    int rend = r0 + 256 < N_NODES ? r0 + 256 : N_NODES;
    float s[8] = {}, q[8] = {}, run[8] = {};
    int curg = -1;
    for (int r = r0 + rh; r < rend; r += 16) {
        uint4 v = *(const uint4*)&Yb[(size_t)r * HDIM + cb];
        unsigned int uu[4] = {v.x, v.y, v.z, v.w};
        float x[8];
        #pragma unroll
        for (int i = 0; i < 4; ++i) {
            float2 f = up2(uu[i]);
            x[2 * i] = f.x; x[2 * i + 1] = f.y;
        }
        int g = sseg[r - r0];
        if (g != curg) {
            if (curg >= 0) {
                float* pp = &pooled[curg * HDIM + cb];
                #pragma unroll
                for (int d = 0; d < 8; ++d) atomicAdd(pp + d, run[d]);
            }
            curg = g;
            #pragma unroll
            for (int d = 0; d < 8; ++d) run[d] = x[d];
        } else {
            #pragma unroll
            for (int d = 0; d < 8; ++d) run[d] += x[d];
        }
        #pragma unroll
        for (int d = 0; d < 8; ++d) {
            s[d] += x[d];
            q[d] = fmaf(x[d], x[d], q[d]);
        }
    }
    if (curg >= 0) {
        float* pp = &pooled[curg * HDIM + cb];
        #pragma unroll
        for (int d = 0; d < 8; ++d) atomicAdd(pp + d, run[d]);
    }
    #pragma unroll
    for (int d = 0; d < 8; ++d) red[t][d] = s[d];
    __syncthreads();
    if (t < 128) {   // channel c = t; group c>>3, dim c&7
        float tot = 0.f;
        #pragma unroll
        for (int i = 0; i < 16; ++i) tot += red[i * 16 + (t >> 3)][t & 7];
        atomicAdd(&sums[t], tot);
    }
    __syncthreads();
    #pragma unroll
    for (int d = 0; d < 8; ++d) red[t][d] = q[d];
    __syncthreads();
    if (t < 128) {
        float tot = 0.f;
        #pragma unroll
        for (int i = 0; i < 16; ++i) tot += red[i * 16 + (t >> 3)][t & 7];
        atomicAdd(&sumsq[t], tot);
    }
}

// ---------------- W-fold only (critical path): blocks 0..63 fold W, block 64 folds fb ----------------
__global__ __launch_bounds__(256) void k_fold(const float* __restrict__ sums,
                                              const float* __restrict__ sumsq,
                                              const float* __restrict__ bng,
                                              const float* __restrict__ bnb,
                                              const float* __restrict__ Wnext,
                                              const float* __restrict__ fbnext,
                                              unsigned short* __restrict__ WLnext,
                                              float* __restrict__ Fbnext) {
    __shared__ float sA[HDIM], sB[HDIM];
    int t = threadIdx.x;
    if (t < HDIM) {
        float mu = sums[t] * (1.f / N_NODES);
        float var = fmaxf(sumsq[t] * (1.f / N_NODES) - mu * mu, 0.f);
        float inv = rsqrtf(var + BN_EPS);
        float a = bng[t] * inv;
        sA[t] = a;
        sB[t] = bnb[t] - a * mu;
    }
    __syncthreads();
    if (blockIdx.x < 64) {
        int idx = blockIdx.x * 256 + t;
        int k = idx >> 7, c = idx & 127;
        WLnext[wl_index(k, c)] = f2bf(sA[k] * Wnext[idx]);
    } else if (t < HDIM) {
        float a = fbnext[t];
        for (int k = 0; k < HDIM; ++k) a = fmaf(sB[k], Wnext[k * HDIM + t], a);
        Fbnext[t] = a;
    }
}

// ---------------- deferred pooled heads: one block per graph, all 3 layers ----------------
__global__ __launch_bounds__(256) void k_heads1(const float* __restrict__ statsAll,
                                                const int* __restrict__ gs,
                                                const float* __restrict__ bng0, const float* __restrict__ bnb0,
                                                const float* __restrict__ bng1, const float* __restrict__ bnb1,
                                                const float* __restrict__ bng2, const float* __restrict__ bnb2,
                                                const float* __restrict__ lw0, const float* __restrict__ lb0,
                                                const float* __restrict__ lw1, const float* __restrict__ lb1,
                                                const float* __restrict__ lw2, const float* __restrict__ lb2,
                                                float* __restrict__ pl_all) {
    __shared__ float sA3[3][HDIM], sB3[3][HDIM];
    __shared__ float red[8][HID];
    int g = blockIdx.x, t = threadIdx.x;
    const float* bngs[3] = {bng0, bng1, bng2};
    const float* bnbs[3] = {bnb0, bnb1, bnb2};
    const float* lws[3] = {lw0, lw1, lw2};
    const float* lbs[3] = {lb0, lb1, lb2};
    if (t < HDIM) {
        #pragma unroll
        for (int l = 0; l < 3; ++l) {
            const float* su = statsAll + (size_t)l * STATS_STRIDE;
            float mu = su[t] * (1.f / N_NODES);
            float var = fmaxf(su[128 + t] * (1.f / N_NODES) - mu * mu, 0.f);
            float inv = rsqrtf(var + BN_EPS);
            float a = bngs[l][t] * inv;
            sA3[l][t] = a;
            sB3[l][t] = bnbs[l][t] - a * mu;
        }
    }
    __syncthreads();
    float cnt = (float)(gs[g + 1] - gs[g]);
    int col = t & 31, kq = t >> 5;
    #pragma unroll
    for (int l = 0; l < 3; ++l) {
        const float* pg = statsAll + (size_t)l * STATS_STRIDE + 256 + (size_t)g * HDIM;
        float part = 0.f;
        #pragma unroll
        for (int kk = 0; kk < 16; ++kk) {
            int k = kq * 16 + kk;
            float pin = fmaf(sA3[l][k], pg[k], cnt * sB3[l][k]);
            part = fmaf(pin, lws[l][k * HID + col], part);
        }
        red[kq][col] = part;
        __syncthreads();
        if (kq == 0) {
            float s = red[0][col] + red[1][col] + red[2][col] + red[3][col]
                    + red[4][col] + red[5][col] + red[6][col] + red[7][col];
            pl_all[((size_t)l * G_GRAPHS + g) * HID + col] = fmaxf(s + lbs[l][col], 0.f);
        }
        __syncthreads();
    }
}

// ---------------- final: BN(pl) -> MLP -> BN -> relu -> logits -> log_softmax ----------------
__global__ __launch_bounds__(256) void k_final(const float* __restrict__ pl_all,
                                               const float* __restrict__ lg0, const float* __restrict__ lbt0,
                                               const float* __restrict__ lg1, const float* __restrict__ lbt1,
                                               const float* __restrict__ lg2, const float* __restrict__ lbt2,
                                               const float* __restrict__ mw1,
                                               const float* __restrict__ mg,
                                               const float* __restrict__ mb,
                                               const float* __restrict__ mw2,
                                               float* __restrict__ out) {
    __shared__ float pl3[3 * G_GRAPHS * HID];   // 24 KB
    __shared__ float w1[3 * HID * HID];         // 12 KB
    __shared__ float hm[G_GRAPHS][HID];         // 8 KB
    __shared__ float sc[96], sh[96];
    __shared__ float lgt[G_GRAPHS][NCLS];
    __shared__ float w2[HID * NCLS];
    int t = threadIdx.x;
    const float* lgs[3] = {lg0, lg1, lg2};
    const float* lbts[3] = {lbt0, lbt1, lbt2};
    for (int i = t; i < 3 * G_GRAPHS * HID; i += 256) pl3[i] = pl_all[i];
    for (int i = t; i < 3 * HID * HID; i += 256) w1[i] = mw1[i];
    for (int i = t; i < HID * NCLS; i += 256) w2[i] = mw2[i];
    __syncthreads();
    if (t < 96) {
        int l = t >> 5, c = t & 31;
        float s = 0.f, q = 0.f;
        for (int g = 0; g < G_GRAPHS; ++g) {
            float v = pl3[(l * G_GRAPHS + g) * HID + c];
            s += v; q = fmaf(v, v, q);
        }
        float mu = s * (1.f / G_GRAPHS);
        float var = fmaxf(q * (1.f / G_GRAPHS) - mu * mu, 0.f);
        float inv = rsqrtf(var + BN_EPS);
        float a = lgs[l][c] * inv;
        sc[t] = a;
        sh[t] = lbts[l][c] - a * mu;
    }
    __syncthreads();
    for (int i = t; i < 3 * G_GRAPHS * HID; i += 256) {
        int l = i / (G_GRAPHS * HID);
        int c = i & 31;
        pl3[i] = fmaf(pl3[i], sc[l * 32 + c], sh[l * 32 + c]);
    }
    __syncthreads();
    for (int i = t; i < G_GRAPHS * HID; i += 256) {
        int g = i >> 5, c = i & 31;
        float acc = 0.f;
        #pragma unroll
        for (int l = 0; l < 3; ++l)
            for (int k = 0; k < HID; ++k)
                acc = fmaf(pl3[(l * G_GRAPHS + g) * HID + k], w1[(l * HID + k) * HID + c], acc);
        hm[g][c] = acc;
    }
    __syncthreads();
    if (t < HID) {
        float s = 0.f, q = 0.f;
        for (int g = 0; g < G_GRAPHS; ++g) {
            float v = hm[g][t];
            s += v; q = fmaf(v, v, q);
        }
        float mu = s * (1.f / G_GRAPHS);
        float var = fmaxf(q * (1.f / G_GRAPHS) - mu * mu, 0.f);
        float inv = rsqrtf(var + BN_EPS);
        float a = mg[t] * inv;
        sc[t] = a;
        sh[t] = mb[t] - a * mu;
    }
    __syncthreads();
    for (int i = t; i < G_GRAPHS * HID; i += 256) {
        int g = i >> 5, c = i & 31;
        hm[g][c] = fmaxf(fmaf(hm[g][c], sc[c], sh[c]), 0.f);
    }
    __syncthreads();
    for (int i = t; i < G_GRAPHS * NCLS; i += 256) {
        int g = i / NCLS, c = i % NCLS;
        float acc = 0.f;
        for (int k = 0; k < HID; ++k) acc = fmaf(hm[g][k], w2[k * NCLS + c], acc);
        lgt[g][c] = acc;
    }
    __syncthreads();
    if (t < G_GRAPHS) {
        float mx = -INFINITY;
        for (int c = 0; c < NCLS; ++c) mx = fmaxf(mx, lgt[t][c]);
        float s = 0.f;
        for (int c = 0; c < NCLS; ++c) s += expf(lgt[t][c] - mx);
        float lse = mx + logf(s);
        for (int c = 0; c < NCLS; ++c) out[t * NCLS + c] = lgt[t][c] - lse;
    }
}

extern "C" void kernel_launch(void* const* d_in, const int* in_sizes, int n_in,
                              void* d_out, int out_size, void* d_ws, size_t ws_size,
                              hipStream_t stream) {
    (void)in_sizes; (void)n_in; (void)out_size; (void)ws_size;
    const float* feat = (const float*)d_in[0];
    const int* src = (const int*)d_in[1];
    const int* dst = (const int*)d_in[2];
    const int* seg = (const int*)d_in[3];
    auto LP = [&](int l, int j) { return (const float*)d_in[4 + 10 * l + j]; };
    const float* mw1 = (const float*)d_in[34];
    const float* mg  = (const float*)d_in[35];
    const float* mb  = (const float*)d_in[36];
    const float* mw2 = (const float*)d_in[37];

    char* p = (char*)d_ws;
    auto alloc = [&](size_t bytes) { char* r = p; p += (bytes + 255) & ~(size_t)255; return r; };
    unsigned short* Hb = (unsigned short*)alloc((size_t)N_NODES * HDIM * 2);
    unsigned short* Yb = (unsigned short*)alloc((size_t)N_NODES * HDIM * 2);
    int*   ssrc   = (int*)alloc((size_t)N_EDGES * 4);
    unsigned int* gbuf = (unsigned int*)alloc((size_t)N_EDGES * 4);
    int*   rp     = (int*)alloc((size_t)(N_NODES + 1) * 4);
    // contiguous zero region: bcnt | statsAll | bcur
    int*   bcnt   = (int*)alloc((size_t)NBUCK * 4);                 // 256 B
    float* statsAll = (float*)alloc((size_t)3 * STATS_STRIDE * 4);  // 101376 B (256-mult)
    int*   bcur   = (int*)alloc((size_t)NBUCK * 4);                 // 256 B
    float* pl_all = (float*)alloc((size_t)3 * G_GRAPHS * HID * 4);
    int*   gs     = (int*)alloc((size_t)(G_GRAPHS + 1) * 4);
    unsigned short* WL = (unsigned short*)alloc((size_t)3 * HDIM * HDIM * 2);
    float* Fb     = (float*)alloc((size_t)3 * HDIM * 4);

    // prep: layer-0 WL (blocks 0-15) + zero bcnt/stats/bcur (16-19) + graph bounds (20)
    k_prep<<<21, 256, 0, stream>>>(LP(0, 0), WL, (unsigned int*)bcnt, seg, gs);
    // bucket histogram + layer-0 GEMM, fused (independent inputs)
    k_mega0<<<NCHUNK + NGB_GEMM, 256, 0, stream>>>(dst, bcnt, WL, feat, LP(0, 1), Hb);
    k_bscatter<<<NCHUNK, 256, 0, stream>>>(dst, src, bcnt, bcur, gbuf);
    k_bsort<<<NBUCK, 256, CAP_OUT * 4, stream>>>(bcnt, gbuf, ssrc, rp);

    for (int l = 0; l < 3; ++l) {
        float* sums   = statsAll + (size_t)l * STATS_STRIDE;
        float* sumsq  = sums + 128;
        float* pooled = sums + 256;
        if (l > 0) {
            k_gemm_mfma<false><<<NGB_GEMM, 256, 0, stream>>>(
                Yb, WL + (size_t)l * HDIM * HDIM, Fb + (size_t)l * HDIM, Hb);
        }
        k_edge<<<(N_NODES + 3) / 4, 256, 0, stream>>>(Hb, rp, ssrc, LP(l, 2), LP(l, 3), Yb);
        k_stats_pool<<<NB_SCAN, 256, 0, stream>>>(Yb, seg, sums, sumsq, pooled);
        if (l < 2) {
            k_fold<<<65, 256, 0, stream>>>(sums, sumsq, LP(l, 4), LP(l, 5),
                                           LP(l + 1, 0), LP(l + 1, 1),
                                           WL + (size_t)(l + 1) * HDIM * HDIM,
                                           Fb + (size_t)(l + 1) * HDIM);
        }
    }
    // deferred heads (off the per-layer critical path)
    k_heads1<<<G_GRAPHS, 256, 0, stream>>>(statsAll, gs,
                                           LP(0, 4), LP(0, 5), LP(1, 4), LP(1, 5), LP(2, 4), LP(2, 5),
                                           LP(0, 6), LP(0, 7), LP(1, 6), LP(1, 7), LP(2, 6), LP(2, 7),
                                           pl_all);
    k_final<<<1, 256, 0, stream>>>(pl_all,
                                   LP(0, 8), LP(0, 9), LP(1, 8), LP(1, 9), LP(2, 8), LP(2, 9),
                                   mw1, mg, mb, mw2, (float*)d_out);
}

// Round 14
// 315.080 us; speedup vs baseline: 1.1506x; 1.0162x over previous
//
#include <hip/hip_runtime.h>
#include <math.h>

#define N_NODES 50000
#define N_EDGES 800000
#define G_GRAPHS 64
#define HDIM 128
#define HID 32
#define NCLS 10
#define BN_EPS 1e-5f
#define SLOPE 0.2f
#define NB_SCAN 196
#define STATS_STRIDE (256 + G_GRAPHS * HDIM)
#define DEFER_THR 8.0f

// bucket sort geometry
#define NBUCK 64
#define NPB 782              // nodes per bucket; 64*782 = 50048 >= N_NODES
#define CH 4096              // edges per scatter chunk
#define NCHUNK 196           // ceil(N_EDGES / CH)
#define NGB_GEMM 782         // gemm blocks: ceil(N_NODES/64)
#define CAP_OUT 13824        // per-bucket sort capacity (mean 12512, sigma 111)
#define NZ_DWORDS (64 + 3 * STATS_STRIDE + 64)   // bcnt | statsAll | bcur

typedef __attribute__((ext_vector_type(8))) short bf16x8;
typedef __attribute__((ext_vector_type(4))) float f32x4;

__device__ __forceinline__ float lrelu(float x) { return fmaxf(x, SLOPE * x); }

__device__ __forceinline__ unsigned short f2bf(float x) {
    unsigned int u = __float_as_uint(x);
    u = (u + 0x7fffu + ((u >> 16) & 1u)) >> 16;
    return (unsigned short)u;
}
__device__ __forceinline__ unsigned int pk2bf(float lo, float hi) {
    unsigned int r;
    asm("v_cvt_pk_bf16_f32 %0, %1, %2" : "=v"(r) : "v"(lo), "v"(hi));
    return r;
}
__device__ __forceinline__ float2 up2(unsigned int u) {
    return make_float2(__uint_as_float(u << 16), __uint_as_float(u & 0xffff0000u));
}
__device__ __forceinline__ float bf2f(unsigned short u) {
    return __uint_as_float((unsigned int)u << 16);
}
__device__ __forceinline__ int wl_index(int k, int c) {
    int lane = ((k >> 3) & 3) * 16 + (c & 15);
    return (((k >> 5) * 8 + (c >> 4)) * 64 + lane) * 8 + (k & 7);
}

// ---------------- MFMA GEMM body: Hb = bf16( X @ W' + fb' ) ----------------
template <bool XF32>
__device__ __forceinline__ void gemm_body(int bid, const void* __restrict__ Xv,
                                          const unsigned short* __restrict__ WL,
                                          const float* __restrict__ fb,
                                          unsigned short* __restrict__ Hb) {
    int t = threadIdx.x;
    int w = t >> 6, lane = t & 63;
    int i16 = lane & 15, kg = lane >> 4;
    int r0w = bid * 64 + w * 16;
    int row = r0w + i16;
    int rowc = row < N_NODES ? row : N_NODES - 1;

    f32x4 acc[8];
    #pragma unroll
    for (int cs = 0; cs < 8; ++cs) acc[cs] = (f32x4){0.f, 0.f, 0.f, 0.f};

    #pragma unroll
    for (int ks = 0; ks < 4; ++ks) {
        union { uint4 u; bf16x8 s; } af;
        if (XF32) {
            const float* xp = (const float*)Xv + (size_t)rowc * HDIM + ks * 32 + kg * 8;
            float4 v0 = *(const float4*)xp;
            float4 v1 = *(const float4*)(xp + 4);
            af.u.x = pk2bf(v0.x, v0.y);
            af.u.y = pk2bf(v0.z, v0.w);
            af.u.z = pk2bf(v1.x, v1.y);
            af.u.w = pk2bf(v1.z, v1.w);
        } else {
            const unsigned short* xp = (const unsigned short*)Xv + (size_t)rowc * HDIM + ks * 32 + kg * 8;
            af.u = *(const uint4*)xp;
        }
        #pragma unroll
        for (int cs = 0; cs < 8; ++cs) {
            union { uint4 u; bf16x8 s; } bw;
            bw.u = *(const uint4*)&WL[(((ks << 3) + cs) * 64 + lane) * 8];
            acc[cs] = __builtin_amdgcn_mfma_f32_16x16x32_bf16(af.s, bw.s, acc[cs], 0, 0, 0);
        }
    }
    #pragma unroll
    for (int cs = 0; cs < 8; ++cs) {
        int col = cs * 16 + i16;
        float bias = fb[col];
        #pragma unroll
        for (int p = 0; p < 4; ++p) {
            int r = r0w + kg * 4 + p;
            if (r < N_NODES) Hb[(size_t)r * HDIM + col] = f2bf(acc[cs][p] + bias);
        }
    }
}

template <bool XF32>
__global__ __launch_bounds__(256) void k_gemm_mfma(const void* __restrict__ Xv,
                                                   const unsigned short* __restrict__ WL,
                                                   const float* __restrict__ fb,
                                                   unsigned short* __restrict__ Hb) {
    gemm_body<XF32>(blockIdx.x, Xv, WL, fb, Hb);
}

// ---------------- prep: blocks 0..15 = layer-0 W prep; 16..19 = zero-fill; 20 = graph bounds ----------------
__global__ __launch_bounds__(256) void k_prep(const float* __restrict__ W,
                                              unsigned short* __restrict__ WL,
                                              unsigned int* __restrict__ zbase,
                                              const int* __restrict__ seg,
                                              int* __restrict__ gs) {
    int bid = blockIdx.x, t = threadIdx.x;
    if (bid < 16) {
        for (int idx = bid * 256 + t; idx < HDIM * HDIM; idx += 16 * 256) {
            int k = idx >> 7, c = idx & 127;
            WL[wl_index(k, c)] = f2bf(W[idx]);
        }
    } else if (bid < 20) {
        for (int i = (bid - 16) * 256 + t; i < NZ_DWORDS; i += 4 * 256) zbase[i] = 0u;
    } else {
        if (t <= G_GRAPHS) {
            int g = t;
            int lo = 0, hi = N_NODES;
            while (lo < hi) {
                int mid = (lo + hi) >> 1;
                if (seg[mid] < g) lo = mid + 1; else hi = mid;
            }
            gs[g] = lo;
        }
    }
}

// ---------------- mega0: bucket histogram (196) + gemm L0 (782) ----------------
__global__ __launch_bounds__(256) void k_mega0(const int* __restrict__ dst,
                                               int* __restrict__ bcnt,
                                               const unsigned short* __restrict__ WL0,
                                               const float* __restrict__ feat,
                                               const float* __restrict__ fb0,
                                               unsigned short* __restrict__ Hb) {
    __shared__ unsigned int h[NBUCK];
    int bid = blockIdx.x;
    int t = threadIdx.x;
    if (bid < NCHUNK) {
        if (t < NBUCK) h[t] = 0;
        __syncthreads();
        int base = bid * CH;
        #pragma unroll
        for (int e = 0; e < 16; ++e) {
            int i = base + e * 256 + t;
            if (i < N_EDGES) {
                int d = dst[i];
                atomicAdd(&h[d / NPB], 1u);
            }
        }
        __syncthreads();
        if (t < NBUCK && h[t]) atomicAdd(&bcnt[t], (int)h[t]);
    } else {
        gemm_body<true>(bid - NCHUNK, feat, WL0, fb0, Hb);
    }
}

// ---------------- scatter into buckets (local bbase scan; bcur is zero-based cursor) ----------------
__global__ __launch_bounds__(256) void k_bscatter(const int* __restrict__ dst,
                                                  const int* __restrict__ src,
                                                  const int* __restrict__ bcnt,
                                                  int* __restrict__ bcur,
                                                  unsigned int* __restrict__ gbuf) {
    __shared__ unsigned int hist[NBUCK];
    __shared__ unsigned int scanB[NBUCK + 1];
    __shared__ int gdelta[NBUCK];
    __shared__ unsigned int cur[NBUCK];
    __shared__ unsigned int ent[CH];
    __shared__ int bb[NBUCK];
    int t = threadIdx.x;
    int base = blockIdx.x * CH;
    unsigned int eb[16], een[16];
    if (t < NBUCK) {
        int v = bcnt[t];
        int inc = v;
        #pragma unroll
        for (int off = 1; off < 64; off <<= 1) {
            int u = __shfl_up(inc, off);
            if (t >= off) inc += u;
        }
        bb[t] = inc - v;   // exclusive global bucket base
        hist[t] = 0;
    }
    __syncthreads();
    #pragma unroll
    for (int e = 0; e < 16; ++e) {
        int i = base + e * 256 + t;
        if (i < N_EDGES) {
            int d = dst[i];
            int s = src[i];
            int b = d / NPB;
            eb[e] = (unsigned int)b;
            een[e] = ((unsigned int)(d - b * NPB) << 17) | (unsigned int)s;
            atomicAdd(&hist[b], 1u);
        } else {
            eb[e] = 0xFFFFFFFFu;
            een[e] = 0;
        }
    }
    __syncthreads();
    if (t < NBUCK) {
        unsigned int v = hist[t];
        unsigned int inc = v;
        #pragma unroll
        for (int off = 1; off < 64; off <<= 1) {
            unsigned int u = __shfl_up(inc, off);
            if ((t & 63) >= off) inc += u;
        }
        scanB[t + 1] = inc;
        if (t == 0) scanB[0] = 0;
    }
    __syncthreads();
    if (t < NBUCK) {
        unsigned int hv = hist[t];
        int gb = bb[t] + (hv ? atomicAdd(&bcur[t], (int)hv) : 0);
        gdelta[t] = gb - (int)scanB[t];
        cur[t] = 0;
    }
    __syncthreads();
    #pragma unroll
    for (int e = 0; e < 16; ++e) {
        if (eb[e] < NBUCK) {
            unsigned int pos = scanB[eb[e]] + atomicAdd(&cur[eb[e]], 1u);
            ent[pos] = een[e];
        }
    }
    __syncthreads();
    unsigned int cntE = scanB[NBUCK];
    #pragma unroll
    for (int e = 0; e < 16; ++e) {
        unsigned int i = (unsigned int)(e * 256 + t);
        if (i < cntE) {
            int lo2 = 0, hi2 = NBUCK;
            while (hi2 - lo2 > 1) {
                int mid = (lo2 + hi2) >> 1;
                if (scanB[mid] <= i) lo2 = mid; else hi2 = mid;
            }
            gbuf[gdelta[lo2] + i] = ent[i];
        }
    }
}

// ---------------- per-bucket counting sort -> ssrc + rowptr (local bbase scan) ----------------
__global__ __launch_bounds__(256) void k_bsort(const int* __restrict__ bcnt,
                                               const unsigned int* __restrict__ gbuf,
                                               int* __restrict__ ssrc,
                                               int* __restrict__ rowptr) {
    extern __shared__ unsigned int sout[];   // CAP_OUT
    __shared__ unsigned int hist[NPB];
    __shared__ unsigned int sbase[NPB + 1];
    __shared__ unsigned int cur[NPB];
    __shared__ unsigned int wsum[4];
    __shared__ int sbb[NBUCK + 1];
    int b = blockIdx.x;
    int t = threadIdx.x;
    if (t < NBUCK) {
        int v = bcnt[t];
        int inc = v;
        #pragma unroll
        for (int off = 1; off < 64; off <<= 1) {
            int u = __shfl_up(inc, off);
            if (t >= off) inc += u;
        }
        sbb[t + 1] = inc;
        if (t == 0) sbb[0] = 0;
    }
    __syncthreads();
    int lo = sbb[b], hi = sbb[b + 1];
    int cnt = hi - lo;
    if (cnt > CAP_OUT) cnt = CAP_OUT;
    for (int i = t; i < NPB; i += 256) { hist[i] = 0; cur[i] = 0; }
    __syncthreads();
    for (int i = t; i < cnt; i += 256) {
        unsigned int e = gbuf[lo + i];
        atomicAdd(&hist[e >> 17], 1u);
    }
    __syncthreads();
    unsigned int loc[4], s = 0;
    #pragma unroll
    for (int j = 0; j < 4; ++j) {
        int idx = t * 4 + j;
        loc[j] = idx < NPB ? hist[idx] : 0;
        s += loc[j];
    }
    unsigned int inc = s;
    #pragma unroll
    for (int off = 1; off < 64; off <<= 1) {
        unsigned int u = __shfl_up(inc, off);
        if ((t & 63) >= off) inc += u;
    }
    int wid = t >> 6;
    if ((t & 63) == 63) wsum[wid] = inc;
    __syncthreads();
    if (t == 0) {
        unsigned int r = 0;
        #pragma unroll
        for (int w = 0; w < 4; ++w) { unsigned int x = wsum[w]; wsum[w] = r; r += x; }
    }
    __syncthreads();
    unsigned int excl = inc - s + wsum[wid];
    #pragma unroll
    for (int j = 0; j < 4; ++j) {
        int idx = t * 4 + j;
        if (idx < NPB) { sbase[idx] = excl; excl += loc[j]; }
    }
    if (t == 255) sbase[NPB] = excl;
    __syncthreads();
    for (int v = t; v < NPB; v += 256) {
        int nid = b * NPB + v;
        if (nid < N_NODES) rowptr[nid] = lo + (int)sbase[v];
    }
    if (b == NBUCK - 1 && t == 0) rowptr[N_NODES] = N_EDGES;
    for (int i = t; i < cnt; i += 256) {
        unsigned int e = gbuf[lo + i];
        unsigned int dl = e >> 17;
        unsigned int pos = sbase[dl] + atomicAdd(&cur[dl], 1u);
        if (pos < (unsigned int)CAP_OUT) sout[pos] = e & 0x1FFFFu;
    }
    __syncthreads();
    for (int i = t; i < cnt; i += 256) ssrc[lo + i] = (int)sout[i];
}

// ---------------- fused edge kernel: 4 edge-slots/wave, 32-bit offsets (saddr form) ----------------
__global__ __launch_bounds__(256) void k_edge(const unsigned short* __restrict__ Hb,
                                              const int* __restrict__ row_ptr,
                                              const int* __restrict__ ssrc,
                                              const float* __restrict__ attn,
                                              const float* __restrict__ ob,
                                              unsigned short* __restrict__ Yb) {
    int wid = blockIdx.x * 4 + (threadIdx.x >> 6);
    if (wid >= N_NODES) return;
    int lane = threadIdx.x & 63;
    int slot = lane >> 4, s16 = lane & 15;
    int d0 = s16 << 3;
    int beg = row_ptr[wid], end = row_ptr[wid + 1];
    int deg = end - beg;
    if (deg == 0) {
        if (slot == 0) {
            float4 o0 = *(const float4*)&ob[d0];
            float4 o1 = *(const float4*)&ob[d0 + 4];
            uint4 w;
            w.x = pk2bf(fmaxf(o0.x, 0.f), fmaxf(o0.y, 0.f));
            w.y = pk2bf(fmaxf(o0.z, 0.f), fmaxf(o0.w, 0.f));
            w.z = pk2bf(fmaxf(o1.x, 0.f), fmaxf(o1.y, 0.f));
            w.w = pk2bf(fmaxf(o1.z, 0.f), fmaxf(o1.w, 0.f));
            *(uint4*)&Yb[wid * HDIM + d0] = w;   // 32-bit offset
        }
        return;
    }
    float er[8], at[8];
    {
        uint4 e = *(const uint4*)&Hb[wid * HDIM + d0];   // 32-bit offset
        unsigned int uu[4] = {e.x, e.y, e.z, e.w};
        #pragma unroll
        for (int i = 0; i < 4; ++i) {
            float2 f = up2(uu[i]);
            er[2 * i] = f.x; er[2 * i + 1] = f.y;
        }
        float4 a0 = *(const float4*)&attn[d0];
        float4 a1 = *(const float4*)&attn[d0 + 4];
        at[0] = a0.x; at[1] = a0.y; at[2] = a0.z; at[3] = a0.w;
        at[4] = a1.x; at[5] = a1.y; at[6] = a1.z; at[7] = a1.w;
    }
    const float NINF = __int_as_float(0xff800000);
    float m = -1e30f, den = 0.f;
    float acc[8] = {0.f, 0.f, 0.f, 0.f, 0.f, 0.f, 0.f, 0.f};
    int nit = (deg + 3) >> 2;
    int j = beg + slot;
    int sa;
    uint4 elc;
    {
        int jc0 = j < end ? j : beg;
        int jc1 = (j + 4) < end ? (j + 4) : beg;
        int s0 = ssrc[jc0];
        sa = ssrc[jc1];
        elc = *(const uint4*)&Hb[s0 * HDIM + d0];   // 32-bit offset
    }
    for (int it = 0; it < nit; ++it) {
        int jc2 = (j + 8) < end ? (j + 8) : beg;
        int sb = ssrc[jc2];
        uint4 eln = *(const uint4*)&Hb[sa * HDIM + d0];   // 32-bit offset
        bool act = j < end;
        float el[8];
        {
            unsigned int uu[4] = {elc.x, elc.y, elc.z, elc.w};
            #pragma unroll
            for (int i = 0; i < 4; ++i) {
                float2 f = up2(uu[i]);
                el[2 * i] = f.x; el[2 * i + 1] = f.y;
            }
        }
        float p = 0.f;
        #pragma unroll
        for (int d = 0; d < 8; ++d) p = fmaf(lrelu(el[d] + er[d]), at[d], p);
        p += __shfl_xor(p, 1);
        p += __shfl_xor(p, 2);
        float e = act ? p : NINF;
        if (__all(e - m <= DEFER_THR)) {
            float q = __expf(e - m);
            den += q;
            #pragma unroll
            for (int d = 0; d < 8; ++d) acc[d] = fmaf(el[d], q, acc[d]);
        } else {
            float nm = fmaxf(m, e);
            float r = __expf(m - nm);
            float q = __expf(e - nm);
            den = fmaf(den, r, q);
            #pragma unroll
            for (int d = 0; d < 8; ++d) acc[d] = fmaf(acc[d], r, el[d] * q);
            m = nm;
        }
        elc = eln; sa = sb; j += 4;
    }
    #pragma unroll
    for (int st = 16; st <= 32; st <<= 1) {
        float m2 = __shfl_xor(m, st);
        float den2 = __shfl_xor(den, st);
        float nm = fmaxf(m, m2);
        float r1 = __expf(m - nm);
        float r2 = __expf(m2 - nm);
        den = den * r1 + den2 * r2;
        #pragma unroll
        for (int d = 0; d < 8; ++d) {
            float a2 = __shfl_xor(acc[d], st);
            acc[d] = acc[d] * r1 + a2 * r2;
        }
        m = nm;
    }
    if (slot == 0) {
        float inv = den > 0.f ? 1.f / den : 0.f;
        float4 o0 = *(const float4*)&ob[d0];
        float4 o1 = *(const float4*)&ob[d0 + 4];
        float o[8] = {o0.x, o0.y, o0.z, o0.w, o1.x, o1.y, o1.z, o1.w};
        float r[8];
        #pragma unroll
        for (int d = 0; d < 8; ++d) r[d] = fmaxf(fmaf(acc[d], inv, o[d]), 0.f);
        uint4 w;
        w.x = pk2bf(r[0], r[1]);
        w.y = pk2bf(r[2], r[3]);
        w.z = pk2bf(r[4], r[5]);
        w.w = pk2bf(r[6], r[7]);
        *(uint4*)&Yb[wid * HDIM + d0] = w;   // 32-bit offset
    }
}

// ---------------- fused BN stats + per-graph sum pool (uint4 loads: 8 ch/thread) ----------------
__global__ __launch_bounds__(256) void k_stats_pool(const unsigned short* __restrict__ Yb,
                                                    const int* __restrict__ seg,
                                                    float* __restrict__ sums,
                                                    float* __restrict__ sumsq,
                                                    float* __restrict__ pooled) {
    __shared__ float red[256][8];   // 8 KB
    __shared__ int sseg[256];
    int t = threadIdx.x;
    int r0 = blockIdx.x * 256;
    if (r0 + t < N_NODES) sseg[t] = seg[r0 + t];
    __syncthreads();
    int c16 = t & 15, rh = t >> 4;   // 8 channels per thread (c16*8..+7), 16-way row split
    int cb = c16 << 3;
    int rend = r0 + 256 < N_NODES ? r0 + 256 : N_NODES;
    float s[8] = {}, q[8] = {}, run[8] = {};
    int curg = -1;
    for (int r = r0 + rh; r < rend; r += 16) {
        uint4 v = *(const uint4*)&Yb[(size_t)r * HDIM + cb];
        unsigned int uu[4] = {v.x, v.y, v.z, v.w};
        float x[8];
        #pragma unroll
        for (int i = 0; i < 4; ++i) {
            float2 f = up2(uu[i]);
            x[2 * i] = f.x; x[2 * i + 1] = f.y;
        }
        int g = sseg[r - r0];
        if (g != curg) {
            if (curg >= 0) {
                float* pp = &pooled[curg * HDIM + cb];
                #pragma unroll
                for (int d = 0; d < 8; ++d) atomicAdd(pp + d, run[d]);
            }
            curg = g;
            #pragma unroll
            for (int d = 0; d < 8; ++d) run[d] = x[d];
        } else {
            #pragma unroll
            for (int d = 0; d < 8; ++d) run[d] += x[d];
        }
        #pragma unroll
        for (int d = 0; d < 8; ++d) {
            s[d] += x[d];
            q[d] = fmaf(x[d], x[d], q[d]);
        }
    }
    if (curg >= 0) {
        float* pp = &pooled[curg * HDIM + cb];
        #pragma unroll
        for (int d = 0; d < 8; ++d) atomicAdd(pp + d, run[d]);
    }
    #pragma unroll
    for (int d = 0; d < 8; ++d) red[t][d] = s[d];
    __syncthreads();
    if (t < 128) {   // channel c = t; group c>>3, dim c&7
        float tot = 0.f;
        #pragma unroll
        for (int i = 0; i < 16; ++i) tot += red[i * 16 + (t >> 3)][t & 7];
        atomicAdd(&sums[t], tot);
    }
    __syncthreads();
    #pragma unroll
    for (int d = 0; d < 8; ++d) red[t][d] = q[d];
    __syncthreads();
    if (t < 128) {
        float tot = 0.f;
        #pragma unroll
        for (int i = 0; i < 16; ++i) tot += red[i * 16 + (t >> 3)][t & 7];
        atomicAdd(&sumsq[t], tot);
    }
}

// ---------------- W-fold only (critical path): blocks 0..63 fold W, block 64 folds fb ----------------
__global__ __launch_bounds__(256) void k_fold(const float* __restrict__ sums,
                                              const float* __restrict__ sumsq,
                                              const float* __restrict__ bng,
                                              const float* __restrict__ bnb,
                                              const float* __restrict__ Wnext,
                                              const float* __restrict__ fbnext,
                                              unsigned short* __restrict__ WLnext,
                                              float* __restrict__ Fbnext) {
    __shared__ float sA[HDIM], sB[HDIM];
    int t = threadIdx.x;
    if (t < HDIM) {
        float mu = sums[t] * (1.f / N_NODES);
        float var = fmaxf(sumsq[t] * (1.f / N_NODES) - mu * mu, 0.f);
        float inv = rsqrtf(var + BN_EPS);
        float a = bng[t] * inv;
        sA[t] = a;
        sB[t] = bnb[t] - a * mu;
    }
    __syncthreads();
    if (blockIdx.x < 64) {
        int idx = blockIdx.x * 256 + t;
        int k = idx >> 7, c = idx & 127;
        WLnext[wl_index(k, c)] = f2bf(sA[k] * Wnext[idx]);
    } else if (t < HDIM) {
        float a = fbnext[t];
        for (int k = 0; k < HDIM; ++k) a = fmaf(sB[k], Wnext[k * HDIM + t], a);
        Fbnext[t] = a;
    }
}

// ---------------- deferred pooled heads: one block per graph, all 3 layers ----------------
__global__ __launch_bounds__(256) void k_heads1(const float* __restrict__ statsAll,
                                                const int* __restrict__ gs,
                                                const float* __restrict__ bng0, const float* __restrict__ bnb0,
                                                const float* __restrict__ bng1, const float* __restrict__ bnb1,
                                                const float* __restrict__ bng2, const float* __restrict__ bnb2,
                                                const float* __restrict__ lw0, const float* __restrict__ lb0,
                                                const float* __restrict__ lw1, const float* __restrict__ lb1,
                                                const float* __restrict__ lw2, const float* __restrict__ lb2,
                                                float* __restrict__ pl_all) {
    __shared__ float sA3[3][HDIM], sB3[3][HDIM];
    __shared__ float red[8][HID];
    int g = blockIdx.x, t = threadIdx.x;
    const float* bngs[3] = {bng0, bng1, bng2};
    const float* bnbs[3] = {bnb0, bnb1, bnb2};
    const float* lws[3] = {lw0, lw1, lw2};
    const float* lbs[3] = {lb0, lb1, lb2};
    if (t < HDIM) {
        #pragma unroll
        for (int l = 0; l < 3; ++l) {
            const float* su = statsAll + (size_t)l * STATS_STRIDE;
            float mu = su[t] * (1.f / N_NODES);
            float var = fmaxf(su[128 + t] * (1.f / N_NODES) - mu * mu, 0.f);
            float inv = rsqrtf(var + BN_EPS);
            float a = bngs[l][t] * inv;
            sA3[l][t] = a;
            sB3[l][t] = bnbs[l][t] - a * mu;
        }
    }
    __syncthreads();
    float cnt = (float)(gs[g + 1] - gs[g]);
    int col = t & 31, kq = t >> 5;
    #pragma unroll
    for (int l = 0; l < 3; ++l) {
        const float* pg = statsAll + (size_t)l * STATS_STRIDE + 256 + (size_t)g * HDIM;
        float part = 0.f;
        #pragma unroll
        for (int kk = 0; kk < 16; ++kk) {
            int k = kq * 16 + kk;
            float pin = fmaf(sA3[l][k], pg[k], cnt * sB3[l][k]);
            part = fmaf(pin, lws[l][k * HID + col], part);
        }
        red[kq][col] = part;
        __syncthreads();
        if (kq == 0) {
            float s = red[0][col] + red[1][col] + red[2][col] + red[3][col]
                    + red[4][col] + red[5][col] + red[6][col] + red[7][col];
            pl_all[((size_t)l * G_GRAPHS + g) * HID + col] = fmaxf(s + lbs[l][col], 0.f);
        }
        __syncthreads();
    }
}

// ---------------- final: BN(pl) -> MLP -> BN -> relu -> logits -> log_softmax ----------------
__global__ __launch_bounds__(256) void k_final(const float* __restrict__ pl_all,
                                               const float* __restrict__ lg0, const float* __restrict__ lbt0,
                                               const float* __restrict__ lg1, const float* __restrict__ lbt1,
                                               const float* __restrict__ lg2, const float* __restrict__ lbt2,
                                               const float* __restrict__ mw1,
                                               const float* __restrict__ mg,
                                               const float* __restrict__ mb,
                                               const float* __restrict__ mw2,
                                               float* __restrict__ out) {
    __shared__ float pl3[3 * G_GRAPHS * HID];   // 24 KB
    __shared__ float w1[3 * HID * HID];         // 12 KB
    __shared__ float hm[G_GRAPHS][HID];         // 8 KB
    __shared__ float sc[96], sh[96];
    __shared__ float lgt[G_GRAPHS][NCLS];
    __shared__ float w2[HID * NCLS];
    int t = threadIdx.x;
    const float* lgs[3] = {lg0, lg1, lg2};
    const float* lbts[3] = {lbt0, lbt1, lbt2};
    for (int i = t; i < 3 * G_GRAPHS * HID; i += 256) pl3[i] = pl_all[i];
    for (int i = t; i < 3 * HID * HID; i += 256) w1[i] = mw1[i];
    for (int i = t; i < HID * NCLS; i += 256) w2[i] = mw2[i];
    __syncthreads();
    if (t < 96) {
        int l = t >> 5, c = t & 31;
        float s = 0.f, q = 0.f;
        for (int g = 0; g < G_GRAPHS; ++g) {
            float v = pl3[(l * G_GRAPHS + g) * HID + c];
            s += v; q = fmaf(v, v, q);
        }
        float mu = s * (1.f / G_GRAPHS);
        float var = fmaxf(q * (1.f / G_GRAPHS) - mu * mu, 0.f);
        float inv = rsqrtf(var + BN_EPS);
        float a = lgs[l][c] * inv;
        sc[t] = a;
        sh[t] = lbts[l][c] - a * mu;
    }
    __syncthreads();
    for (int i = t; i < 3 * G_GRAPHS * HID; i += 256) {
        int l = i / (G_GRAPHS * HID);
        int c = i & 31;
        pl3[i] = fmaf(pl3[i], sc[l * 32 + c], sh[l * 32 + c]);
    }
    __syncthreads();
    for (int i = t; i < G_GRAPHS * HID; i += 256) {
        int g = i >> 5, c = i & 31;
        float acc = 0.f;
        #pragma unroll
        for (int l = 0; l < 3; ++l)
            for (int k = 0; k < HID; ++k)
                acc = fmaf(pl3[(l * G_GRAPHS + g) * HID + k], w1[(l * HID + k) * HID + c], acc);
        hm[g][c] = acc;
    }
    __syncthreads();
    if (t < HID) {
        float s = 0.f, q = 0.f;
        for (int g = 0; g < G_GRAPHS; ++g) {
            float v = hm[g][t];
            s += v; q = fmaf(v, v, q);
        }
        float mu = s * (1.f / G_GRAPHS);
        float var = fmaxf(q * (1.f / G_GRAPHS) - mu * mu, 0.f);
        float inv = rsqrtf(var + BN_EPS);
        float a = mg[t] * inv;
        sc[t] = a;
        sh[t] = mb[t] - a * mu;
    }
    __syncthreads();
    for (int i = t; i < G_GRAPHS * HID; i += 256) {
        int g = i >> 5, c = i & 31;
        hm[g][c] = fmaxf(fmaf(hm[g][c], sc[c], sh[c]), 0.f);
    }
    __syncthreads();
    for (int i = t; i < G_GRAPHS * NCLS; i += 256) {
        int g = i / NCLS, c = i % NCLS;
        float acc = 0.f;
        for (int k = 0; k < HID; ++k) acc = fmaf(hm[g][k], w2[k * NCLS + c], acc);
        lgt[g][c] = acc;
    }
    __syncthreads();
    if (t < G_GRAPHS) {
        float mx = -INFINITY;
        for (int c = 0; c < NCLS; ++c) mx = fmaxf(mx, lgt[t][c]);
        float s = 0.f;
        for (int c = 0; c < NCLS; ++c) s += expf(lgt[t][c] - mx);
        float lse = mx + logf(s);
        for (int c = 0; c < NCLS; ++c) out[t * NCLS + c] = lgt[t][c] - lse;
    }
}

extern "C" void kernel_launch(void* const* d_in, const int* in_sizes, int n_in,
                              void* d_out, int out_size, void* d_ws, size_t ws_size,
                              hipStream_t stream) {
    (void)in_sizes; (void)n_in; (void)out_size; (void)ws_size;
    const float* feat = (const float*)d_in[0];
    const int* src = (const int*)d_in[1];
    const int* dst = (const int*)d_in[2];
    const int* seg = (const int*)d_in[3];
    auto LP = [&](int l, int j) { return (const float*)d_in[4 + 10 * l + j]; };
    const float* mw1 = (const float*)d_in[34];
    const float* mg  = (const float*)d_in[35];
    const float* mb  = (const float*)d_in[36];
    const float* mw2 = (const float*)d_in[37];

    char* p = (char*)d_ws;
    auto alloc = [&](size_t bytes) { char* r = p; p += (bytes + 255) & ~(size_t)255; return r; };
    unsigned short* Hb = (unsigned short*)alloc((size_t)N_NODES * HDIM * 2);
    unsigned short* Yb = (unsigned short*)alloc((size_t)N_NODES * HDIM * 2);
    int*   ssrc   = (int*)alloc((size_t)N_EDGES * 4);
    unsigned int* gbuf = (unsigned int*)alloc((size_t)N_EDGES * 4);
    int*   rp     = (int*)alloc((size_t)(N_NODES + 1) * 4);
    // contiguous zero region: bcnt | statsAll | bcur
    int*   bcnt   = (int*)alloc((size_t)NBUCK * 4);                 // 256 B
    float* statsAll = (float*)alloc((size_t)3 * STATS_STRIDE * 4);  // 101376 B (256-mult)
    int*   bcur   = (int*)alloc((size_t)NBUCK * 4);                 // 256 B
    float* pl_all = (float*)alloc((size_t)3 * G_GRAPHS * HID * 4);
    int*   gs     = (int*)alloc((size_t)(G_GRAPHS + 1) * 4);
    unsigned short* WL = (unsigned short*)alloc((size_t)3 * HDIM * HDIM * 2);
    float* Fb     = (float*)alloc((size_t)3 * HDIM * 4);

    // prep: layer-0 WL (blocks 0-15) + zero bcnt/stats/bcur (16-19) + graph bounds (20)
    k_prep<<<21, 256, 0, stream>>>(LP(0, 0), WL, (unsigned int*)bcnt, seg, gs);
    // bucket histogram + layer-0 GEMM, fused (independent inputs)
    k_mega0<<<NCHUNK + NGB_GEMM, 256, 0, stream>>>(dst, bcnt, WL, feat, LP(0, 1), Hb);
    k_bscatter<<<NCHUNK, 256, 0, stream>>>(dst, src, bcnt, bcur, gbuf);
    k_bsort<<<NBUCK, 256, CAP_OUT * 4, stream>>>(bcnt, gbuf, ssrc, rp);

    for (int l = 0; l < 3; ++l) {
        float* sums   = statsAll + (size_t)l * STATS_STRIDE;
        float* sumsq  = sums + 128;
        float* pooled = sums + 256;
        if (l > 0) {
            k_gemm_mfma<false><<<NGB_GEMM, 256, 0, stream>>>(
                Yb, WL + (size_t)l * HDIM * HDIM, Fb + (size_t)l * HDIM, Hb);
        }
        k_edge<<<(N_NODES + 3) / 4, 256, 0, stream>>>(Hb, rp, ssrc, LP(l, 2), LP(l, 3), Yb);
        k_stats_pool<<<NB_SCAN, 256, 0, stream>>>(Yb, seg, sums, sumsq, pooled);
        if (l < 2) {
            k_fold<<<65, 256, 0, stream>>>(sums, sumsq, LP(l, 4), LP(l, 5),
                                           LP(l + 1, 0), LP(l + 1, 1),
                                           WL + (size_t)(l + 1) * HDIM * HDIM,
                                           Fb + (size_t)(l + 1) * HDIM);
        }
    }
    // deferred heads (off the per-layer critical path)
    k_heads1<<<G_GRAPHS, 256, 0, stream>>>(statsAll, gs,
                                           LP(0, 4), LP(0, 5), LP(1, 4), LP(1, 5), LP(2, 4), LP(2, 5),
                                           LP(0, 6), LP(0, 7), LP(1, 6), LP(1, 7), LP(2, 6), LP(2, 7),
                                           pl_all);
    k_final<<<1, 256, 0, stream>>>(pl_all,
                                   LP(0, 8), LP(0, 9), LP(1, 8), LP(1, 9), LP(2, 8), LP(2, 9),
                                   mw1, mg, mb, mw2, (float*)d_out);
}

// Round 15
// 312.819 us; speedup vs baseline: 1.1589x; 1.0072x over previous
//
#include <hip/hip_runtime.h>
#include <math.h>

#define N_NODES 50000
#define N_EDGES 800000
#define G_GRAPHS 64
#define HDIM 128
#define HID 32
#define NCLS 10
#define BN_EPS 1e-5f
#define SLOPE 0.2f
#define NB_SCAN 196
#define STATS_STRIDE (256 + G_GRAPHS * HDIM)
#define DEFER_THR 8.0f

// bucket sort geometry
#define NBUCK 64
#define NPB 782              // nodes per bucket; 64*782 = 50048 >= N_NODES
#define CH 4096              // edges per scatter chunk
#define NCHUNK 196           // ceil(N_EDGES / CH)
#define NGB_GEMM 782         // gemm blocks: ceil(N_NODES/64)
#define CAP_OUT 13824        // per-bucket sort capacity (mean 12512, sigma 111)
#define NZ_DWORDS (64 + 3 * STATS_STRIDE + 64)   // bcnt | statsAll | bcur

typedef __attribute__((ext_vector_type(8))) short bf16x8;
typedef __attribute__((ext_vector_type(4))) float f32x4;

__device__ __forceinline__ float lrelu(float x) { return fmaxf(x, SLOPE * x); }

__device__ __forceinline__ unsigned short f2bf(float x) {
    unsigned int u = __float_as_uint(x);
    u = (u + 0x7fffu + ((u >> 16) & 1u)) >> 16;
    return (unsigned short)u;
}
__device__ __forceinline__ unsigned int pk2bf(float lo, float hi) {
    unsigned int r;
    asm("v_cvt_pk_bf16_f32 %0, %1, %2" : "=v"(r) : "v"(lo), "v"(hi));
    return r;
}
__device__ __forceinline__ float2 up2(unsigned int u) {
    return make_float2(__uint_as_float(u << 16), __uint_as_float(u & 0xffff0000u));
}
__device__ __forceinline__ float bf2f(unsigned short u) {
    return __uint_as_float((unsigned int)u << 16);
}
__device__ __forceinline__ int wl_index(int k, int c) {
    int lane = ((k >> 3) & 3) * 16 + (c & 15);
    return (((k >> 5) * 8 + (c >> 4)) * 64 + lane) * 8 + (k & 7);
}

// ---------------- MFMA GEMM body: Hb = bf16( X @ W' + fb' ) ----------------
template <bool XF32>
__device__ __forceinline__ void gemm_body(int bid, const void* __restrict__ Xv,
                                          const unsigned short* __restrict__ WL,
                                          const float* __restrict__ fb,
                                          unsigned short* __restrict__ Hb) {
    int t = threadIdx.x;
    int w = t >> 6, lane = t & 63;
    int i16 = lane & 15, kg = lane >> 4;
    int r0w = bid * 64 + w * 16;
    int row = r0w + i16;
    int rowc = row < N_NODES ? row : N_NODES - 1;

    f32x4 acc[8];
    #pragma unroll
    for (int cs = 0; cs < 8; ++cs) acc[cs] = (f32x4){0.f, 0.f, 0.f, 0.f};

    #pragma unroll
    for (int ks = 0; ks < 4; ++ks) {
        union { uint4 u; bf16x8 s; } af;
        if (XF32) {
            const float* xp = (const float*)Xv + (size_t)rowc * HDIM + ks * 32 + kg * 8;
            float4 v0 = *(const float4*)xp;
            float4 v1 = *(const float4*)(xp + 4);
            af.u.x = pk2bf(v0.x, v0.y);
            af.u.y = pk2bf(v0.z, v0.w);
            af.u.z = pk2bf(v1.x, v1.y);
            af.u.w = pk2bf(v1.z, v1.w);
        } else {
            const unsigned short* xp = (const unsigned short*)Xv + (size_t)rowc * HDIM + ks * 32 + kg * 8;
            af.u = *(const uint4*)xp;
        }
        #pragma unroll
        for (int cs = 0; cs < 8; ++cs) {
            union { uint4 u; bf16x8 s; } bw;
            bw.u = *(const uint4*)&WL[(((ks << 3) + cs) * 64 + lane) * 8];
            acc[cs] = __builtin_amdgcn_mfma_f32_16x16x32_bf16(af.s, bw.s, acc[cs], 0, 0, 0);
        }
    }
    #pragma unroll
    for (int cs = 0; cs < 8; ++cs) {
        int col = cs * 16 + i16;
        float bias = fb[col];
        #pragma unroll
        for (int p = 0; p < 4; ++p) {
            int r = r0w + kg * 4 + p;
            if (r < N_NODES) Hb[(size_t)r * HDIM + col] = f2bf(acc[cs][p] + bias);
        }
    }
}

template <bool XF32>
__global__ __launch_bounds__(256) void k_gemm_mfma(const void* __restrict__ Xv,
                                                   const unsigned short* __restrict__ WL,
                                                   const float* __restrict__ fb,
                                                   unsigned short* __restrict__ Hb) {
    gemm_body<XF32>(blockIdx.x, Xv, WL, fb, Hb);
}

// ---------------- prep: blocks 0..15 = layer-0 W prep; 16..19 = zero-fill; 20 = graph bounds ----------------
__global__ __launch_bounds__(256) void k_prep(const float* __restrict__ W,
                                              unsigned short* __restrict__ WL,
                                              unsigned int* __restrict__ zbase,
                                              const int* __restrict__ seg,
                                              int* __restrict__ gs) {
    int bid = blockIdx.x, t = threadIdx.x;
    if (bid < 16) {
        for (int idx = bid * 256 + t; idx < HDIM * HDIM; idx += 16 * 256) {
            int k = idx >> 7, c = idx & 127;
            WL[wl_index(k, c)] = f2bf(W[idx]);
        }
    } else if (bid < 20) {
        for (int i = (bid - 16) * 256 + t; i < NZ_DWORDS; i += 4 * 256) zbase[i] = 0u;
    } else {
        if (t <= G_GRAPHS) {
            int g = t;
            int lo = 0, hi = N_NODES;
            while (lo < hi) {
                int mid = (lo + hi) >> 1;
                if (seg[mid] < g) lo = mid + 1; else hi = mid;
            }
            gs[g] = lo;
        }
    }
}

// ---------------- mega0: bucket histogram (196) + gemm L0 (782) ----------------
__global__ __launch_bounds__(256) void k_mega0(const int* __restrict__ dst,
                                               int* __restrict__ bcnt,
                                               const unsigned short* __restrict__ WL0,
                                               const float* __restrict__ feat,
                                               const float* __restrict__ fb0,
                                               unsigned short* __restrict__ Hb) {
    __shared__ unsigned int h[NBUCK];
    int bid = blockIdx.x;
    int t = threadIdx.x;
    if (bid < NCHUNK) {
        if (t < NBUCK) h[t] = 0;
        __syncthreads();
        int base = bid * CH;
        #pragma unroll
        for (int e = 0; e < 16; ++e) {
            int i = base + e * 256 + t;
            if (i < N_EDGES) {
                int d = dst[i];
                atomicAdd(&h[d / NPB], 1u);
            }
        }
        __syncthreads();
        if (t < NBUCK && h[t]) atomicAdd(&bcnt[t], (int)h[t]);
    } else {
        gemm_body<true>(bid - NCHUNK, feat, WL0, fb0, Hb);
    }
}

// ---------------- scatter into buckets (local bbase scan; bcur is zero-based cursor) ----------------
__global__ __launch_bounds__(256) void k_bscatter(const int* __restrict__ dst,
                                                  const int* __restrict__ src,
                                                  const int* __restrict__ bcnt,
                                                  int* __restrict__ bcur,
                                                  unsigned int* __restrict__ gbuf) {
    __shared__ unsigned int hist[NBUCK];
    __shared__ unsigned int scanB[NBUCK + 1];
    __shared__ int gdelta[NBUCK];
    __shared__ unsigned int cur[NBUCK];
    __shared__ unsigned int ent[CH];
    __shared__ int bb[NBUCK];
    int t = threadIdx.x;
    int base = blockIdx.x * CH;
    unsigned int eb[16], een[16];
    if (t < NBUCK) {
        int v = bcnt[t];
        int inc = v;
        #pragma unroll
        for (int off = 1; off < 64; off <<= 1) {
            int u = __shfl_up(inc, off);
            if (t >= off) inc += u;
        }
        bb[t] = inc - v;   // exclusive global bucket base
        hist[t] = 0;
    }
    __syncthreads();
    #pragma unroll
    for (int e = 0; e < 16; ++e) {
        int i = base + e * 256 + t;
        if (i < N_EDGES) {
            int d = dst[i];
            int s = src[i];
            int b = d / NPB;
            eb[e] = (unsigned int)b;
            een[e] = ((unsigned int)(d - b * NPB) << 17) | (unsigned int)s;
            atomicAdd(&hist[b], 1u);
        } else {
            eb[e] = 0xFFFFFFFFu;
            een[e] = 0;
        }
    }
    __syncthreads();
    if (t < NBUCK) {
        unsigned int v = hist[t];
        unsigned int inc = v;
        #pragma unroll
        for (int off = 1; off < 64; off <<= 1) {
            unsigned int u = __shfl_up(inc, off);
            if ((t & 63) >= off) inc += u;
        }
        scanB[t + 1] = inc;
        if (t == 0) scanB[0] = 0;
    }
    __syncthreads();
    if (t < NBUCK) {
        unsigned int hv = hist[t];
        int gb = bb[t] + (hv ? atomicAdd(&bcur[t], (int)hv) : 0);
        gdelta[t] = gb - (int)scanB[t];
        cur[t] = 0;
    }
    __syncthreads();
    #pragma unroll
    for (int e = 0; e < 16; ++e) {
        if (eb[e] < NBUCK) {
            unsigned int pos = scanB[eb[e]] + atomicAdd(&cur[eb[e]], 1u);
            ent[pos] = een[e];
        }
    }
    __syncthreads();
    unsigned int cntE = scanB[NBUCK];
    #pragma unroll
    for (int e = 0; e < 16; ++e) {
        unsigned int i = (unsigned int)(e * 256 + t);
        if (i < cntE) {
            int lo2 = 0, hi2 = NBUCK;
            while (hi2 - lo2 > 1) {
                int mid = (lo2 + hi2) >> 1;
                if (scanB[mid] <= i) lo2 = mid; else hi2 = mid;
            }
            gbuf[gdelta[lo2] + i] = ent[i];
        }
    }
}

// ---------------- per-bucket counting sort -> ssrc + rowptr (local bbase scan) ----------------
__global__ __launch_bounds__(256) void k_bsort(const int* __restrict__ bcnt,
                                               const unsigned int* __restrict__ gbuf,
                                               int* __restrict__ ssrc,
                                               int* __restrict__ rowptr) {
    extern __shared__ unsigned int sout[];   // CAP_OUT
    __shared__ unsigned int hist[NPB];
    __shared__ unsigned int sbase[NPB + 1];
    __shared__ unsigned int cur[NPB];
    __shared__ unsigned int wsum[4];
    __shared__ int sbb[NBUCK + 1];
    int b = blockIdx.x;
    int t = threadIdx.x;
    if (t < NBUCK) {
        int v = bcnt[t];
        int inc = v;
        #pragma unroll
        for (int off = 1; off < 64; off <<= 1) {
            int u = __shfl_up(inc, off);
            if (t >= off) inc += u;
        }
        sbb[t + 1] = inc;
        if (t == 0) sbb[0] = 0;
    }
    __syncthreads();
    int lo = sbb[b], hi = sbb[b + 1];
    int cnt = hi - lo;
    if (cnt > CAP_OUT) cnt = CAP_OUT;
    for (int i = t; i < NPB; i += 256) { hist[i] = 0; cur[i] = 0; }
    __syncthreads();
    for (int i = t; i < cnt; i += 256) {
        unsigned int e = gbuf[lo + i];
        atomicAdd(&hist[e >> 17], 1u);
    }
    __syncthreads();
    unsigned int loc[4], s = 0;
    #pragma unroll
    for (int j = 0; j < 4; ++j) {
        int idx = t * 4 + j;
        loc[j] = idx < NPB ? hist[idx] : 0;
        s += loc[j];
    }
    unsigned int inc = s;
    #pragma unroll
    for (int off = 1; off < 64; off <<= 1) {
        unsigned int u = __shfl_up(inc, off);
        if ((t & 63) >= off) inc += u;
    }
    int wid = t >> 6;
    if ((t & 63) == 63) wsum[wid] = inc;
    __syncthreads();
    if (t == 0) {
        unsigned int r = 0;
        #pragma unroll
        for (int w = 0; w < 4; ++w) { unsigned int x = wsum[w]; wsum[w] = r; r += x; }
    }
    __syncthreads();
    unsigned int excl = inc - s + wsum[wid];
    #pragma unroll
    for (int j = 0; j < 4; ++j) {
        int idx = t * 4 + j;
        if (idx < NPB) { sbase[idx] = excl; excl += loc[j]; }
    }
    if (t == 255) sbase[NPB] = excl;
    __syncthreads();
    for (int v = t; v < NPB; v += 256) {
        int nid = b * NPB + v;
        if (nid < N_NODES) rowptr[nid] = lo + (int)sbase[v];
    }
    if (b == NBUCK - 1) {
        if (t == 0) rowptr[N_NODES] = N_EDGES;
        if (t < 16) ssrc[N_EDGES + t] = 0;   // zero pad: k_edge prefetches read up to +12 unclamped
    }
    for (int i = t; i < cnt; i += 256) {
        unsigned int e = gbuf[lo + i];
        unsigned int dl = e >> 17;
        unsigned int pos = sbase[dl] + atomicAdd(&cur[dl], 1u);
        if (pos < (unsigned int)CAP_OUT) sout[pos] = e & 0x1FFFFu;
    }
    __syncthreads();
    for (int i = t; i < cnt; i += 256) ssrc[lo + i] = (int)sout[i];
}

// ---------------- fused edge kernel: 4 edge-slots/wave, 32-bit offsets, unclamped padded prefetch ----------------
__global__ __launch_bounds__(256) void k_edge(const unsigned short* __restrict__ Hb,
                                              const int* __restrict__ row_ptr,
                                              const int* __restrict__ ssrc,
                                              const float* __restrict__ attn,
                                              const float* __restrict__ ob,
                                              unsigned short* __restrict__ Yb) {
    int wid = blockIdx.x * 4 + (threadIdx.x >> 6);
    if (wid >= N_NODES) return;
    int lane = threadIdx.x & 63;
    int slot = lane >> 4, s16 = lane & 15;
    int d0 = s16 << 3;
    int beg = row_ptr[wid], end = row_ptr[wid + 1];
    int deg = end - beg;
    if (deg == 0) {
        if (slot == 0) {
            float4 o0 = *(const float4*)&ob[d0];
            float4 o1 = *(const float4*)&ob[d0 + 4];
            uint4 w;
            w.x = pk2bf(fmaxf(o0.x, 0.f), fmaxf(o0.y, 0.f));
            w.y = pk2bf(fmaxf(o0.z, 0.f), fmaxf(o0.w, 0.f));
            w.z = pk2bf(fmaxf(o1.x, 0.f), fmaxf(o1.y, 0.f));
            w.w = pk2bf(fmaxf(o1.z, 0.f), fmaxf(o1.w, 0.f));
            *(uint4*)&Yb[wid * HDIM + d0] = w;
        }
        return;
    }
    float er[8], at[8];
    {
        uint4 e = *(const uint4*)&Hb[wid * HDIM + d0];
        unsigned int uu[4] = {e.x, e.y, e.z, e.w};
        #pragma unroll
        for (int i = 0; i < 4; ++i) {
            float2 f = up2(uu[i]);
            er[2 * i] = f.x; er[2 * i + 1] = f.y;
        }
        float4 a0 = *(const float4*)&attn[d0];
        float4 a1 = *(const float4*)&attn[d0 + 4];
        at[0] = a0.x; at[1] = a0.y; at[2] = a0.z; at[3] = a0.w;
        at[4] = a1.x; at[5] = a1.y; at[6] = a1.z; at[7] = a1.w;
    }
    const float NINF = __int_as_float(0xff800000);
    float m = -1e30f, den = 0.f;
    float acc[8] = {0.f, 0.f, 0.f, 0.f, 0.f, 0.f, 0.f, 0.f};
    int nit = (deg + 3) >> 2;
    int j = beg + slot;
    // unclamped prefetch: ssrc is zero-padded by 16 past N_EDGES; stale rows discarded via act
    int sa = ssrc[j + 4];
    uint4 elc = *(const uint4*)&Hb[ssrc[j] * HDIM + d0];
    for (int it = 0; it < nit; ++it) {
        int sb = ssrc[j + 8];
        uint4 eln = *(const uint4*)&Hb[sa * HDIM + d0];
        bool act = j < end;
        float el[8];
        {
            unsigned int uu[4] = {elc.x, elc.y, elc.z, elc.w};
            #pragma unroll
            for (int i = 0; i < 4; ++i) {
                float2 f = up2(uu[i]);
                el[2 * i] = f.x; el[2 * i + 1] = f.y;
            }
        }
        float p = 0.f;
        #pragma unroll
        for (int d = 0; d < 8; ++d) p = fmaf(lrelu(el[d] + er[d]), at[d], p);
        p += __shfl_xor(p, 1);
        p += __shfl_xor(p, 2);
        float e = act ? p : NINF;
        if (__all(e - m <= DEFER_THR)) {
            float q = __expf(e - m);
            den += q;
            #pragma unroll
            for (int d = 0; d < 8; ++d) acc[d] = fmaf(el[d], q, acc[d]);
        } else {
            float nm = fmaxf(m, e);
            float r = __expf(m - nm);
            float q = __expf(e - nm);
            den = fmaf(den, r, q);
            #pragma unroll
            for (int d = 0; d < 8; ++d) acc[d] = fmaf(acc[d], r, el[d] * q);
            m = nm;
        }
        elc = eln; sa = sb; j += 4;
    }
    #pragma unroll
    for (int st = 16; st <= 32; st <<= 1) {
        float m2 = __shfl_xor(m, st);
        float den2 = __shfl_xor(den, st);
        float nm = fmaxf(m, m2);
        float r1 = __expf(m - nm);
        float r2 = __expf(m2 - nm);
        den = den * r1 + den2 * r2;
        #pragma unroll
        for (int d = 0; d < 8; ++d) {
            float a2 = __shfl_xor(acc[d], st);
            acc[d] = acc[d] * r1 + a2 * r2;
        }
        m = nm;
    }
    if (slot == 0) {
        float inv = den > 0.f ? 1.f / den : 0.f;
        float4 o0 = *(const float4*)&ob[d0];
        float4 o1 = *(const float4*)&ob[d0 + 4];
        float o[8] = {o0.x, o0.y, o0.z, o0.w, o1.x, o1.y, o1.z, o1.w};
        float r[8];
        #pragma unroll
        for (int d = 0; d < 8; ++d) r[d] = fmaxf(fmaf(acc[d], inv, o[d]), 0.f);
        uint4 w;
        w.x = pk2bf(r[0], r[1]);
        w.y = pk2bf(r[2], r[3]);
        w.z = pk2bf(r[4], r[5]);
        w.w = pk2bf(r[6], r[7]);
        *(uint4*)&Yb[wid * HDIM + d0] = w;
    }
}

// ---------------- fused BN stats + per-graph sum pool (uint4 loads: 8 ch/thread) ----------------
__global__ __launch_bounds__(256) void k_stats_pool(const unsigned short* __restrict__ Yb,
                                                    const int* __restrict__ seg,
                                                    float* __restrict__ sums,
                                                    float* __restrict__ sumsq,
                                                    float* __restrict__ pooled) {
    __shared__ float red[256][8];   // 8 KB
    __shared__ int sseg[256];
    int t = threadIdx.x;
    int r0 = blockIdx.x * 256;
    if (r0 + t < N_NODES) sseg[t] = seg[r0 + t];
    __syncthreads();
    int c16 = t & 15, rh = t >> 4;   // 8 channels per thread (c16*8..+7), 16-way row split
    int cb = c16 << 3;
    int rend = r0 + 256 < N_NODES ? r0 + 256 : N_NODES;
    float s[8] = {}, q[8] = {}, run[8] = {};
    int curg = -1;
    for (int r = r0 + rh; r < rend; r += 16) {
        uint4 v = *(const uint4*)&Yb[(size_t)r * HDIM + cb];
        unsigned int uu[4] = {v.x, v.y, v.z, v.w};
        float x[8];
        #pragma unroll
        for (int i = 0; i < 4; ++i) {
            float2 f = up2(uu[i]);
            x[2 * i] = f.x; x[2 * i + 1] = f.y;
        }
        int g = sseg[r - r0];
        if (g != curg) {
            if (curg >= 0) {
                float* pp = &pooled[curg * HDIM + cb];
                #pragma unroll
                for (int d = 0; d < 8; ++d) atomicAdd(pp + d, run[d]);
            }
            curg = g;
            #pragma unroll
            for (int d = 0; d < 8; ++d) run[d] = x[d];
        } else {
            #pragma unroll
            for (int d = 0; d < 8; ++d) run[d] += x[d];
        }
        #pragma unroll
        for (int d = 0; d < 8; ++d) {
            s[d] += x[d];
            q[d] = fmaf(x[d], x[d], q[d]);
        }
    }
    if (curg >= 0) {
        float* pp = &pooled[curg * HDIM + cb];
        #pragma unroll
        for (int d = 0; d < 8; ++d) atomicAdd(pp + d, run[d]);
    }
    #pragma unroll
    for (int d = 0; d < 8; ++d) red[t][d] = s[d];
    __syncthreads();
    if (t < 128) {   // channel c = t; group c>>3, dim c&7
        float tot = 0.f;
        #pragma unroll
        for (int i = 0; i < 16; ++i) tot += red[i * 16 + (t >> 3)][t & 7];
        atomicAdd(&sums[t], tot);
    }
    __syncthreads();
    #pragma unroll
    for (int d = 0; d < 8; ++d) red[t][d] = q[d];
    __syncthreads();
    if (t < 128) {
        float tot = 0.f;
        #pragma unroll
        for (int i = 0; i < 16; ++i) tot += red[i * 16 + (t >> 3)][t & 7];
        atomicAdd(&sumsq[t], tot);
    }
}

// ---------------- W-fold only (critical path): blocks 0..63 fold W, block 64 folds fb ----------------
__global__ __launch_bounds__(256) void k_fold(const float* __restrict__ sums,
                                              const float* __restrict__ sumsq,
                                              const float* __restrict__ bng,
                                              const float* __restrict__ bnb,
                                              const float* __restrict__ Wnext,
                                              const float* __restrict__ fbnext,
                                              unsigned short* __restrict__ WLnext,
                                              float* __restrict__ Fbnext) {
    __shared__ float sA[HDIM], sB[HDIM];
    int t = threadIdx.x;
    if (t < HDIM) {
        float mu = sums[t] * (1.f / N_NODES);
        float var = fmaxf(sumsq[t] * (1.f / N_NODES) - mu * mu, 0.f);
        float inv = rsqrtf(var + BN_EPS);
        float a = bng[t] * inv;
        sA[t] = a;
        sB[t] = bnb[t] - a * mu;
    }
    __syncthreads();
    if (blockIdx.x < 64) {
        int idx = blockIdx.x * 256 + t;
        int k = idx >> 7, c = idx & 127;
        WLnext[wl_index(k, c)] = f2bf(sA[k] * Wnext[idx]);
    } else if (t < HDIM) {
        float a = fbnext[t];
        for (int k = 0; k < HDIM; ++k) a = fmaf(sB[k], Wnext[k * HDIM + t], a);
        Fbnext[t] = a;
    }
}

// ---------------- deferred pooled heads: one block per graph, all 3 layers ----------------
__global__ __launch_bounds__(256) void k_heads1(const float* __restrict__ statsAll,
                                                const int* __restrict__ gs,
                                                const float* __restrict__ bng0, const float* __restrict__ bnb0,
                                                const float* __restrict__ bng1, const float* __restrict__ bnb1,
                                                const float* __restrict__ bng2, const float* __restrict__ bnb2,
                                                const float* __restrict__ lw0, const float* __restrict__ lb0,
                                                const float* __restrict__ lw1, const float* __restrict__ lb1,
                                                const float* __restrict__ lw2, const float* __restrict__ lb2,
                                                float* __restrict__ pl_all) {
    __shared__ float sA3[3][HDIM], sB3[3][HDIM];
    __shared__ float red[8][HID];
    int g = blockIdx.x, t = threadIdx.x;
    const float* bngs[3] = {bng0, bng1, bng2};
    const float* bnbs[3] = {bnb0, bnb1, bnb2};
    const float* lws[3] = {lw0, lw1, lw2};
    const float* lbs[3] = {lb0, lb1, lb2};
    if (t < HDIM) {
        #pragma unroll
        for (int l = 0; l < 3; ++l) {
            const float* su = statsAll + (size_t)l * STATS_STRIDE;
            float mu = su[t] * (1.f / N_NODES);
            float var = fmaxf(su[128 + t] * (1.f / N_NODES) - mu * mu, 0.f);
            float inv = rsqrtf(var + BN_EPS);
            float a = bngs[l][t] * inv;
            sA3[l][t] = a;
            sB3[l][t] = bnbs[l][t] - a * mu;
        }
    }
    __syncthreads();
    float cnt = (float)(gs[g + 1] - gs[g]);
    int col = t & 31, kq = t >> 5;
    #pragma unroll
    for (int l = 0; l < 3; ++l) {
        const float* pg = statsAll + (size_t)l * STATS_STRIDE + 256 + (size_t)g * HDIM;
        float part = 0.f;
        #pragma unroll
        for (int kk = 0; kk < 16; ++kk) {
            int k = kq * 16 + kk;
            float pin = fmaf(sA3[l][k], pg[k], cnt * sB3[l][k]);
            part = fmaf(pin, lws[l][k * HID + col], part);
        }
        red[kq][col] = part;
        __syncthreads();
        if (kq == 0) {
            float s = red[0][col] + red[1][col] + red[2][col] + red[3][col]
                    + red[4][col] + red[5][col] + red[6][col] + red[7][col];
            pl_all[((size_t)l * G_GRAPHS + g) * HID + col] = fmaxf(s + lbs[l][col], 0.f);
        }
        __syncthreads();
    }
}

// ---------------- final: BN(pl) -> MLP -> BN -> relu -> logits -> log_softmax ----------------
__global__ __launch_bounds__(256) void k_final(const float* __restrict__ pl_all,
                                               const float* __restrict__ lg0, const float* __restrict__ lbt0,
                                               const float* __restrict__ lg1, const float* __restrict__ lbt1,
                                               const float* __restrict__ lg2, const float* __restrict__ lbt2,
                                               const float* __restrict__ mw1,
                                               const float* __restrict__ mg,
                                               const float* __restrict__ mb,
                                               const float* __restrict__ mw2,
                                               float* __restrict__ out) {
    __shared__ float pl3[3 * G_GRAPHS * HID];   // 24 KB
    __shared__ float w1[3 * HID * HID];         // 12 KB
    __shared__ float hm[G_GRAPHS][HID];         // 8 KB
    __shared__ float sc[96], sh[96];
    __shared__ float lgt[G_GRAPHS][NCLS];
    __shared__ float w2[HID * NCLS];
    int t = threadIdx.x;
    const float* lgs[3] = {lg0, lg1, lg2};
    const float* lbts[3] = {lbt0, lbt1, lbt2};
    for (int i = t; i < 3 * G_GRAPHS * HID; i += 256) pl3[i] = pl_all[i];
    for (int i = t; i < 3 * HID * HID; i += 256) w1[i] = mw1[i];
    for (int i = t; i < HID * NCLS; i += 256) w2[i] = mw2[i];
    __syncthreads();
    if (t < 96) {
        int l = t >> 5, c = t & 31;
        float s = 0.f, q = 0.f;
        for (int g = 0; g < G_GRAPHS; ++g) {
            float v = pl3[(l * G_GRAPHS + g) * HID + c];
            s += v; q = fmaf(v, v, q);
        }
        float mu = s * (1.f / G_GRAPHS);
        float var = fmaxf(q * (1.f / G_GRAPHS) - mu * mu, 0.f);
        float inv = rsqrtf(var + BN_EPS);
        float a = lgs[l][c] * inv;
        sc[t] = a;
        sh[t] = lbts[l][c] - a * mu;
    }
    __syncthreads();
    for (int i = t; i < 3 * G_GRAPHS * HID; i += 256) {
        int l = i / (G_GRAPHS * HID);
        int c = i & 31;
        pl3[i] = fmaf(pl3[i], sc[l * 32 + c], sh[l * 32 + c]);
    }
    __syncthreads();
    for (int i = t; i < G_GRAPHS * HID; i += 256) {
        int g = i >> 5, c = i & 31;
        float acc = 0.f;
        #pragma unroll
        for (int l = 0; l < 3; ++l)
            for (int k = 0; k < HID; ++k)
                acc = fmaf(pl3[(l * G_GRAPHS + g) * HID + k], w1[(l * HID + k) * HID + c], acc);
        hm[g][c] = acc;
    }
    __syncthreads();
    if (t < HID) {
        float s = 0.f, q = 0.f;
        for (int g = 0; g < G_GRAPHS; ++g) {
            float v = hm[g][t];
            s += v; q = fmaf(v, v, q);
        }
        float mu = s * (1.f / G_GRAPHS);
        float var = fmaxf(q * (1.f / G_GRAPHS) - mu * mu, 0.f);
        float inv = rsqrtf(var + BN_EPS);
        float a = mg[t] * inv;
        sc[t] = a;
        sh[t] = mb[t] - a * mu;
    }
    __syncthreads();
    for (int i = t; i < G_GRAPHS * HID; i += 256) {
        int g = i >> 5, c = i & 31;
        hm[g][c] = fmaxf(fmaf(hm[g][c], sc[c], sh[c]), 0.f);
    }
    __syncthreads();
    for (int i = t; i < G_GRAPHS * NCLS; i += 256) {
        int g = i / NCLS, c = i % NCLS;
        float acc = 0.f;
        for (int k = 0; k < HID; ++k) acc = fmaf(hm[g][k], w2[k * NCLS + c], acc);
        lgt[g][c] = acc;
    }
    __syncthreads();
    if (t < G_GRAPHS) {
        float mx = -INFINITY;
        for (int c = 0; c < NCLS; ++c) mx = fmaxf(mx, lgt[t][c]);
        float s = 0.f;
        for (int c = 0; c < NCLS; ++c) s += expf(lgt[t][c] - mx);
        float lse = mx + logf(s);
        for (int c = 0; c < NCLS; ++c) out[t * NCLS + c] = lgt[t][c] - lse;
    }
}

extern "C" void kernel_launch(void* const* d_in, const int* in_sizes, int n_in,
                              void* d_out, int out_size, void* d_ws, size_t ws_size,
                              hipStream_t stream) {
    (void)in_sizes; (void)n_in; (void)out_size; (void)ws_size;
    const float* feat = (const float*)d_in[0];
    const int* src = (const int*)d_in[1];
    const int* dst = (const int*)d_in[2];
    const int* seg = (const int*)d_in[3];
    auto LP = [&](int l, int j) { return (const float*)d_in[4 + 10 * l + j]; };
    const float* mw1 = (const float*)d_in[34];
    const float* mg  = (const float*)d_in[35];
    const float* mb  = (const float*)d_in[36];
    const float* mw2 = (const float*)d_in[37];

    char* p = (char*)d_ws;
    auto alloc = [&](size_t bytes) { char* r = p; p += (bytes + 255) & ~(size_t)255; return r; };
    unsigned short* Hb = (unsigned short*)alloc((size_t)N_NODES * HDIM * 2);
    unsigned short* Yb = (unsigned short*)alloc((size_t)N_NODES * HDIM * 2);
    int*   ssrc   = (int*)alloc((size_t)(N_EDGES + 16) * 4);   // +16 zero pad for unclamped prefetch
    unsigned int* gbuf = (unsigned int*)alloc((size_t)N_EDGES * 4);
    int*   rp     = (int*)alloc((size_t)(N_NODES + 1) * 4);
    // contiguous zero region: bcnt | statsAll | bcur
    int*   bcnt   = (int*)alloc((size_t)NBUCK * 4);                 // 256 B
    float* statsAll = (float*)alloc((size_t)3 * STATS_STRIDE * 4);  // 101376 B (256-mult)
    int*   bcur   = (int*)alloc((size_t)NBUCK * 4);                 // 256 B
    float* pl_all = (float*)alloc((size_t)3 * G_GRAPHS * HID * 4);
    int*   gs     = (int*)alloc((size_t)(G_GRAPHS + 1) * 4);
    unsigned short* WL = (unsigned short*)alloc((size_t)3 * HDIM * HDIM * 2);
    float* Fb     = (float*)alloc((size_t)3 * HDIM * 4);

    // prep: layer-0 WL (blocks 0-15) + zero bcnt/stats/bcur (16-19) + graph bounds (20)
    k_prep<<<21, 256, 0, stream>>>(LP(0, 0), WL, (unsigned int*)bcnt, seg, gs);
    // bucket histogram + layer-0 GEMM, fused (independent inputs)
    k_mega0<<<NCHUNK + NGB_GEMM, 256, 0, stream>>>(dst, bcnt, WL, feat, LP(0, 1), Hb);
    k_bscatter<<<NCHUNK, 256, 0, stream>>>(dst, src, bcnt, bcur, gbuf);
    k_bsort<<<NBUCK, 256, CAP_OUT * 4, stream>>>(bcnt, gbuf, ssrc, rp);

    for (int l = 0; l < 3; ++l) {
        float* sums   = statsAll + (size_t)l * STATS_STRIDE;
        float* sumsq  = sums + 128;
        float* pooled = sums + 256;
        if (l > 0) {
            k_gemm_mfma<false><<<NGB_GEMM, 256, 0, stream>>>(
                Yb, WL + (size_t)l * HDIM * HDIM, Fb + (size_t)l * HDIM, Hb);
        }
        k_edge<<<(N_NODES + 3) / 4, 256, 0, stream>>>(Hb, rp, ssrc, LP(l, 2), LP(l, 3), Yb);
        k_stats_pool<<<NB_SCAN, 256, 0, stream>>>(Yb, seg, sums, sumsq, pooled);
        if (l < 2) {
            k_fold<<<65, 256, 0, stream>>>(sums, sumsq, LP(l, 4), LP(l, 5),
                                           LP(l + 1, 0), LP(l + 1, 1),
                                           WL + (size_t)(l + 1) * HDIM * HDIM,
                                           Fb + (size_t)(l + 1) * HDIM);
        }
    }
    // deferred heads (off the per-layer critical path)
    k_heads1<<<G_GRAPHS, 256, 0, stream>>>(statsAll, gs,
                                           LP(0, 4), LP(0, 5), LP(1, 4), LP(1, 5), LP(2, 4), LP(2, 5),
                                           LP(0, 6), LP(0, 7), LP(1, 6), LP(1, 7), LP(2, 6), LP(2, 7),
                                           pl_all);
    k_final<<<1, 256, 0, stream>>>(pl_all,
                                   LP(0, 8), LP(0, 9), LP(1, 8), LP(1, 9), LP(2, 8), LP(2, 9),
                                   mw1, mg, mb, mw2, (float*)d_out);
}